// Round 1
// 330.834 us; speedup vs baseline: 1.0202x; 1.0202x over previous
//
#include <hip/hip_runtime.h>
#include <hip/hip_fp16.h>
#include <math.h>

// DiagonalLSTM: B=8, Cin=HID=128, H=64, W=64, K=2, T = 2W-1 = 127 steps.
//
// Round 15 design (round 14 + barrier-drain removal):
//   - per-step __syncthreads() replaced by {s_waitcnt lgkmcnt(0); raw
//     s_barrier}: __syncthreads emits a full vmcnt(0) drain which forced the
//     just-issued zph prefetch load (~600-900cy L3), the out stores and the
//     hx export store to complete inside every serial step. Only LDS
//     visibility (lgkmcnt) is actually required at the step barrier; the hx
//     protocol is sentinel-validated (data==flag) and out/zph need no
//     cross-wave ordering. Stores/loads now stay in flight across steps.
//   - zph prefetch for t+1 issued at the TOP of the step (right after the
//     zu->zf conversion frees the registers) so MFMA+gates (~1500cy) cover
//     its latency instead of it stalling next step's convert.
//   - otherwise the proven R10/R12/R13/R14 loop: 32 blocks x 512 thr,
//     sentinel hx exchange (fire-and-forget, zero drains), 1 barrier/step,
//     boundary+zp prefetched 1 step ahead, bias folded into zph, incremental
//     pointers, MFMA intrinsics, reg-buffered out stores, clamp-free
//     fsig/ftanh.

#define HID 128
#define BB 8
#define HH 64
#define WW 64
#define TT 127

typedef _Float16 v8h __attribute__((ext_vector_type(8)));
typedef float v4f __attribute__((ext_vector_type(4)));

#define SENT64 0xFFFFFFFFFFFFFFFFULL  // 4x f16 -NaN (0xFF fill pattern)

__device__ __forceinline__ float fsig(float x) {
  // saturates correctly at +/-inf without clamping; never NaN
  float e = __builtin_amdgcn_exp2f(x * -1.44269504f);
  return __builtin_amdgcn_rcpf(1.f + e);
}
__device__ __forceinline__ float ftanh_(float x) {
  // 1 - 2/(1+exp2(2x*log2e)): NaN-free at +/-inf (unlike (e-1)/(e+1))
  float e = __builtin_amdgcn_exp2f(x * 2.88539009f);
  return __builtin_fmaf(-2.f, __builtin_amdgcn_rcpf(1.f + e), 1.f);
}

// ---- prep_w2: w_ss frags + w_is frags + zph bias slot + bsum + hx fill ----
__global__ __launch_bounds__(256) void prep_w2(const float* __restrict__ w_ss,
                                               const float* __restrict__ w_is,
                                               const float* __restrict__ b_is,
                                               const float* __restrict__ b_ss,
                                               _Float16* __restrict__ wp,
                                               _Float16* __restrict__ wisa,
                                               __half* __restrict__ zph,
                                               float* __restrict__ bsum512,
                                               unsigned long long* __restrict__ hx) {
  int idx = blockIdx.x * 256 + threadIdx.x;
  if (idx < 131072) {
    // w_ss -> Wcat(512x256) A-frags: wp[(((mt*8+kt)*64+L)*8+j)]
    int j = idx & 7;
    int L = (idx >> 3) & 63;
    int kt = (idx >> 9) & 7;
    int mt = idx >> 12;  // 0..31
    int O = mt * 16 + (L & 15);
    int k = kt * 32 + ((L >> 4) & 3) * 8 + j;
    float v = (k < 128) ? w_ss[(size_t)O * 256 + k * 2]
                        : w_ss[(size_t)O * 256 + (k - 128) * 2 + 1];
    wp[idx] = (_Float16)v;
  } else if (idx < 196608) {
    // w_is (512x128) A-frags: wisa[(((mt*4+kt)*64+L)*8+j)]
    int i2 = idx - 131072;
    int j = i2 & 7;
    int L = (i2 >> 3) & 63;
    int kt = (i2 >> 9) & 3;
    int mt = i2 >> 11;  // 0..31
    int O = mt * 16 + (L & 15);
    int k = kt * 32 + ((L >> 4) & 3) * 8 + j;
    wisa[i2] = (_Float16)w_is[(size_t)O * 128 + k];
  } else if (idx < 197120) {
    // zph bias slot: layout idx2 = (u>>2)*16 + g*4 + (u&3)
    int idx2 = idx - 196608;  // 0..511
    int g = (idx2 >> 2) & 3;
    int u = (idx2 >> 4) * 4 + (idx2 & 3);
    int O = g * 128 + u;
    zph[(size_t)BB * HH * WW * 512 + idx2] = __float2half(b_is[O] + b_ss[O]);
  } else if (idx < 197632) {
    int O = idx - 197120;
    bsum512[O] = b_is[O] + b_ss[O];
  } else if (idx < 197632 + 130048) {
    // hx sentinel fill: 260096 u64 as 130048 x 16B
    int j = idx - 197632;
    uint4 s;
    s.x = 0xFFFFFFFFu;
    s.y = 0xFFFFFFFFu;
    s.z = 0xFFFFFFFFu;
    s.w = 0xFFFFFFFFu;
    ((uint4*)hx)[j] = s;
  }
}

// ---- zpre_mfma: zph[pos*512 + (u>>2)*16 + g*4 + (u&3)] = z + bias ----
__global__ __launch_bounds__(256) void zpre_mfma(const float* __restrict__ x,
                                                 const _Float16* __restrict__ wisa,
                                                 const float* __restrict__ bsum512,
                                                 __half* __restrict__ zph) {
  const int b = blockIdx.x >> 6;
  const int r = blockIdx.x & 63;
  const int tid = threadIdx.x;
  const int wv = tid >> 6;  // 0..3 -> ntile
  const int L = tid & 63;
  const int quad = L >> 4;
  const int l15 = L & 15;

  __shared__ _Float16 xt[64][136];  // [w][c] f16, padded
  __shared__ float bs[512];

  if (tid < 128) {
    *(float4*)&bs[tid * 4] = *(const float4*)&bsum512[tid * 4];
  }
  // stage x(b,:,r,:) -> xt transposed; coalesced 16-lane c-row reads
  {
    const int cw = tid >> 4;        // c within pass
    const int w4 = (tid & 15) * 4;  // w base
#pragma unroll
    for (int p = 0; p < 8; p++) {
      int c = p * 16 + cw;
      float4 v = *(const float4*)&x[(((size_t)b * 128 + c) * HH + r) * WW + w4];
      xt[w4 + 0][c] = (_Float16)v.x;
      xt[w4 + 1][c] = (_Float16)v.y;
      xt[w4 + 2][c] = (_Float16)v.z;
      xt[w4 + 3][c] = (_Float16)v.w;
    }
  }
  __syncthreads();

  const int wcol = wv * 16 + l15;  // B-side n
  v8h bf[4];
#pragma unroll
  for (int kt = 0; kt < 4; kt++)
    bf[kt] = *(const v8h*)&xt[wcol][kt * 32 + quad * 8];

  const size_t pos = ((size_t)b * HH + r) * WW + wcol;
  const v8h* wa8 = (const v8h*)wisa;

#pragma unroll 4
  for (int mt = 0; mt < 32; mt++) {
    v4f acc = (v4f){0.f, 0.f, 0.f, 0.f};
#pragma unroll
    for (int kt = 0; kt < 4; kt++) {
      v8h af = wa8[((size_t)mt * 4 + kt) * 64 + L];
      acc = __builtin_amdgcn_mfma_f32_16x16x32_f16(af, bf[kt], acc, 0, 0, 0);
    }
    // O = mt*16 + quad*4 + reg; add bias, pack, store
    float4 bv = *(float4*)&bs[mt * 16 + quad * 4];
    __half2 lo = __floats2half2_rn(acc[0] + bv.x, acc[1] + bv.y);
    __half2 hi = __floats2half2_rn(acc[2] + bv.z, acc[3] + bv.w);
    uint2 pk;
    pk.x = *(unsigned*)&lo;
    pk.y = *(unsigned*)&hi;
    *(uint2*)&zph[pos * 512 + ((mt & 7) * 4 + quad) * 16 + (mt >> 3) * 4] = pk;
  }
}

// ---------------- persistent MFMA recurrent kernel -------------
#define HROW 136  // padded row stride in halfs

// Step barrier: LDS-visibility only. __syncthreads() would emit a full
// s_waitcnt vmcnt(0) drain, serializing the zph prefetch / out stores /
// hx export into every serial step. None of those need ordering here:
//   - h_lds cross-wave visibility  -> lgkmcnt(0) + s_barrier (this macro)
//   - hx exchange                  -> sentinel-validated by the consumer
//   - out / zph                    -> no cross-wave consumers
// The trailing empty asm (memory clobber) keeps next-step DS ops from being
// hoisted above the barrier (cf. rule #18).
#define STEP_BARRIER()                                   \
  do {                                                   \
    asm volatile("s_waitcnt lgkmcnt(0)" ::: "memory");   \
    __builtin_amdgcn_s_barrier();                        \
    asm volatile("" ::: "memory");                       \
  } while (0)

__global__ __launch_bounds__(512, 1) void lstm_mfma(
    const __half* __restrict__ zph, const _Float16* __restrict__ wp,
    unsigned long long* __restrict__ hx,  // [TT][8][4][64], sentinel-filled
    float* __restrict__ out) {
  const int blk = blockIdx.x;  // 0..31
  const int rgr = blk >> 2;    // row group 0..7 (rows 8*rgr .. +7)
  const int bg = blk & 3;      // batch group 0..3 (b = 2*bg, 2*bg+1)
  const int R0 = rgr * 8;
  const int tid = threadIdx.x;
  const int wv = tid >> 6;  // wave 0..7
  const int L = tid & 63;
  const int quad = L >> 4;
  const int l15 = L & 15;
  const int rl = l15 >> 1;  // cell row-local 0..7
  const int bl = l15 & 1;   // cell batch-local 0..1
  const int b = bg * 2 + bl;
  const int r = R0 + rl;
  const int uq0 = 16 * wv + quad * 4;     // D-side unit base (+reg)
  const int zoff = (4 * wv + quad) * 16;  // zp contiguous 16-half group

  // double-buffered: slot s holds row R0-1+s (s=0..8), per b-local
  __shared__ _Float16 h_lds[2][9 * 2 * HROW];
  for (int i = tid; i < (2 * 9 * 2 * HROW) / 2; i += 512)
    ((unsigned*)h_lds)[i] = 0u;

  // ---- weights as A-fragments, loaded once ----
  v8h wfrag[4][8];
  {
    const v8h* wp8 = (const v8h*)wp;
#pragma unroll
    for (int g = 0; g < 4; g++)
#pragma unroll
      for (int kt = 0; kt < 8; kt++)
        wfrag[g][kt] = wp8[((size_t)((8 * g + wv) * 8 + kt)) * 64 + L];
  }

  float c[4] = {0.f, 0.f, 0.f, 0.f};
  float4 outb[4];  // shift-window out buffer (w-3..w per cell)
#pragma unroll
  for (int i = 0; i < 4; i++) outb[i] = make_float4(0.f, 0.f, 0.f, 0.f);

  const int ebl = L >> 5;       // boundary consumer: b-local
  const int eu = (L & 31) * 4;  // boundary consumer: unit base
  const int exp_idx = bl * 32 + 4 * wv + quad;  // producer slot (l15>=14)

  const bool is_cons = (wv == 0) && (rgr > 0);

  // ---- incremental pointers ----
  const __half* zpp = zph + ((size_t)b * HH + r) * WW * 512 + zoff;
  const __half* zbias = zph + (size_t)BB * HH * WW * 512 + zoff;
  const unsigned long long* ca =
      hx + (((size_t)(rgr > 0 ? rgr - 1 : 0) * 4 + bg) * 64 + L);  // hx[t]
  unsigned long long* pa = hx + (((size_t)rgr * 4 + bg) * 64 + exp_idx);
  float* op0 = out + (((size_t)b * HID + uq0 + 0) * HH + r) * WW;
  float* op1 = out + (((size_t)b * HID + uq0 + 1) * HH + r) * WW;
  float* op2 = out + (((size_t)b * HID + uq0 + 2) * HH + r) * WW;
  float* op3 = out + (((size_t)b * HID + uq0 + 3) * HH + r) * WW;

  // ---- zp for t=0 (w0 = -r: in-band only for r==0) ----
  union ZU {
    uint4 q[2];
    __half h[16];  // h[g*4 + rg2]
  } zu;
  {
    const uint4* p0 = (const uint4*)((r == 0) ? zpp : zbias);
    zu.q[0] = p0[0];
    zu.q[1] = p0[1];
  }
  int wn = 1 - r;  // next-step w
  const __half* zcur = zpp + (ptrdiff_t)wn * 512;

  // ---- boundary pipeline: pend = load of hx[t=0] ----
  unsigned long long pend = 0ull;
  if (is_cons) {
    pend = __hip_atomic_load(ca, __ATOMIC_RELAXED, __HIP_MEMORY_SCOPE_AGENT);
  }

  __syncthreads();

  for (int t = 0; t < TT; t++) {
    const int rb = t & 1;
    const int wb = rb ^ 1;

    // ---- issue next boundary load (hx[t+1], consumed end of t+1) ----
    unsigned long long newp = 0ull;
    if (is_cons && (t + 1) < TT) {
      newp = __hip_atomic_load(ca + 2048, __ATOMIC_RELAXED,
                               __HIP_MEMORY_SCOPE_AGENT);
    }

    // ---- convert zu -> float early (co-issues under MFMA) ----
    float zf[16];
#pragma unroll
    for (int i = 0; i < 16; i++) zf[i] = __half2float(zu.h[i]);

    // ---- zp prefetch for t+1, issued at TOP of step: its ~600-900cy L3
    // latency is covered by the MFMA+gate phase below instead of landing at
    // the step boundary (contiguous 32B; bias slot when out-of-band) ----
    {
      const uint4* p = (const uint4*)(((unsigned)wn < WW) ? zcur : zbias);
      zu.q[0] = p[0];
      zu.q[1] = p[1];
      wn++;
      zcur += 512;
    }

    // ---- MFMA: kt 0..3 -> rows r-1 (slot rl); kt 4..7 -> rows r (slot rl+1)
    v4f acc[4];
#pragma unroll
    for (int g = 0; g < 4; g++) acc[g] = (v4f){0.f, 0.f, 0.f, 0.f};
#pragma unroll
    for (int kt = 0; kt < 8; kt++) {
      const int slot = (kt < 4) ? rl : (rl + 1);
      v8h bf = *(const v8h*)&h_lds[rb][(slot * 2 + bl) * HROW +
                                       (kt & 3) * 32 + quad * 8];
#pragma unroll
      for (int g = 0; g < 4; g++)
        acc[g] = __builtin_amdgcn_mfma_f32_16x16x32_f16(wfrag[g][kt], bf,
                                                        acc[g], 0, 0, 0);
    }

    // ---- gates (bias pre-folded into zph/zf) ----
    const int w = t - r;
    const bool inband = ((unsigned)w < WW);
    float hv[4];
#pragma unroll
    for (int rg2 = 0; rg2 < 4; rg2++) {
      float z0 = acc[0][rg2] + zf[0 * 4 + rg2];
      float z1 = acc[1][rg2] + zf[1 * 4 + rg2];
      float z2 = acc[2][rg2] + zf[2 * 4 + rg2];
      float z3 = acc[3][rg2] + zf[3 * 4 + rg2];
      float iv = fsig(z0);
      float fv = fsig(z1);
      float ov = fsig(z2);
      float gv = ftanh_(z3);
      c[rg2] = fv * c[rg2] + iv * gv;
      hv[rg2] = ov * ftanh_(c[rg2]);
    }

    // ---- h(t) -> wb slots 1..8 (LDS, 8B per lane) ----
    __half2 plo = __floats2half2_rn(hv[0], hv[1]);
    __half2 phi = __floats2half2_rn(hv[2], hv[3]);
    {
      uint2 pk;
      pk.x = *(unsigned*)&plo;
      pk.y = *(unsigned*)&phi;
      *(uint2*)&h_lds[wb][((rl + 1) * 2 + bl) * HROW + uq0] = pk;
    }

    // ---- export h(t)[R0+7]: fire-and-forget (data == flag, no drain) ----
    if (rgr < 7 && l15 >= 14) {
      unsigned long long pk =
          ((unsigned long long)*(unsigned*)&phi << 32) | *(unsigned*)&plo;
      __hip_atomic_store(pa, pk, __ATOMIC_RELAXED, __HIP_MEMORY_SCOPE_AGENT);
    }
    pa += 2048;

    // ---- out shift-window; coalesced 16B flush every 4 steps per cell ----
#pragma unroll
    for (int rg2 = 0; rg2 < 4; rg2++) {
      outb[rg2].x = outb[rg2].y;
      outb[rg2].y = outb[rg2].z;
      outb[rg2].z = outb[rg2].w;
      outb[rg2].w = hv[rg2];
    }
    if (inband && (w & 3) == 3) {
      *(float4*)op0 = outb[0];
      *(float4*)op1 = outb[1];
      *(float4*)op2 = outb[2];
      *(float4*)op3 = outb[3];
      op0 += 4;
      op1 += 4;
      op2 += 4;
      op3 += 4;
    }

    // ---- validate pend (hx[t] = h(t)[R0-1]), write to wb slot 0 ----
    if (is_cons) {
      while (__ballot(pend == SENT64) != 0ull) {
        __builtin_amdgcn_s_sleep(1);
        pend = __hip_atomic_load(ca, __ATOMIC_RELAXED,
                                 __HIP_MEMORY_SCOPE_AGENT);
      }
      *(unsigned long long*)&h_lds[wb][(0 * 2 + ebl) * HROW + eu] = pend;
      pend = newp;
    }
    ca += 2048;

    // ---- LDS-only step barrier: no vmcnt drain (see macro comment) ----
    STEP_BARRIER();  // wb complete; rb free for rewrite next step
  }
}

// ================= round-1 fallback path (proven correct) =================
__global__ __launch_bounds__(256) void transpose_x(const float* __restrict__ x,
                                                   float* __restrict__ xT) {
  int b = blockIdx.x >> 6;
  int r = blockIdx.x & 63;
  __shared__ float tile[32][65];
  for (int cc = 0; cc < 4; cc++) {
    int cl = threadIdx.x >> 6;
    int w = threadIdx.x & 63;
#pragma unroll
    for (int k = 0; k < 8; k++) {
      int c_loc = k * 4 + cl;
      int c = cc * 32 + c_loc;
      tile[c_loc][w] = x[(((size_t)b * 128 + c) * HH + r) * WW + w];
    }
    __syncthreads();
    int cs = threadIdx.x & 31;
    int wp = threadIdx.x >> 5;
#pragma unroll
    for (int k = 0; k < 8; k++) {
      int w2 = wp * 8 + k;
      xT[(((size_t)b * HH + r) * WW + w2) * 128 + cc * 32 + cs] = tile[cs][w2];
    }
    __syncthreads();
  }
}

__global__ __launch_bounds__(256) void step_kernel(
    const float* __restrict__ x, const float* __restrict__ xT, int use_xT,
    const float* __restrict__ w_is, const float* __restrict__ b_is,
    const float* __restrict__ w_ss, const float* __restrict__ b_ss,
    const float* __restrict__ h_prev, float* __restrict__ h_next,
    float* __restrict__ c_state, float* __restrict__ out, int t) {
  const int rg = blockIdx.x;
  const int q = blockIdx.y;
  const int r0 = rg * 2;
  const int tid = threadIdx.x;
  const int o_loc = tid & 63;
  const int k4 = tid >> 6;
  const int g_ = o_loc >> 4;
  const int u_ = o_loc & 15;
  const int O = g_ * 128 + q * 16 + u_;
  const int i0 = k4 * 32;

  __shared__ __align__(16) float h_in[3][BB][HID];
  __shared__ float zred[16][4][65];

  for (int idx = tid; idx < 3 * BB * HID; idx += 256) {
    int row_sel = idx >> 10;
    int rem = idx & 1023;
    int b = rem >> 7;
    int u = rem & 127;
    int rr = r0 - 1 + row_sel;
    h_in[row_sel][b][u] = (rr >= 0) ? h_prev[((size_t)b * HH + rr) * HID + u] : 0.0f;
  }

  float wr0[32], wr1[32], wz[32];
  {
    const float4* wss4 = (const float4*)(w_ss + ((size_t)O * 128 + i0) * 2);
#pragma unroll
    for (int j = 0; j < 16; j++) {
      float4 v = wss4[j];
      wr0[2 * j] = v.x;
      wr1[2 * j] = v.y;
      wr0[2 * j + 1] = v.z;
      wr1[2 * j + 1] = v.w;
    }
    const float4* wis4 = (const float4*)(w_is + (size_t)O * 128 + i0);
#pragma unroll
    for (int j = 0; j < 8; j++) {
      float4 v = wis4[j];
      wz[4 * j] = v.x;
      wz[4 * j + 1] = v.y;
      wz[4 * j + 2] = v.z;
      wz[4 * j + 3] = v.w;
    }
  }

  __syncthreads();

  float acc[2][BB];
#pragma unroll
  for (int rl = 0; rl < 2; rl++)
#pragma unroll
    for (int b = 0; b < BB; b++) acc[rl][b] = 0.0f;

#pragma unroll
  for (int jb = 0; jb < 8; jb++) {
    int ib = i0 + jb * 4;
#pragma unroll
    for (int b = 0; b < BB; b++) {
      const float4 hm4 = *(const float4*)&h_in[0][b][ib];
      const float4 hc4 = *(const float4*)&h_in[1][b][ib];
      const float4 hp4 = *(const float4*)&h_in[2][b][ib];
      const float* hm = (const float*)&hm4;
      const float* hc = (const float*)&hc4;
      const float* hq = (const float*)&hp4;
#pragma unroll
      for (int jj = 0; jj < 4; jj++) {
        float w0v = wr0[jb * 4 + jj];
        float w1v = wr1[jb * 4 + jj];
        acc[0][b] += w0v * hm[jj] + w1v * hc[jj];
        acc[1][b] += w0v * hc[jj] + w1v * hq[jj];
      }
    }
  }

#pragma unroll
  for (int rl = 0; rl < 2; rl++) {
    int rr = r0 + rl;
    int wcol = t - rr;
    if (wcol >= 0 && wcol < WW) {
      if (use_xT) {
        for (int b = 0; b < BB; b++) {
          const float4* xp =
              (const float4*)(xT + (((size_t)b * HH + rr) * WW + wcol) * 128 + i0);
#pragma unroll
          for (int j = 0; j < 8; j++) {
            float4 v = xp[j];
            acc[rl][b] += wz[4 * j] * v.x + wz[4 * j + 1] * v.y +
                          wz[4 * j + 2] * v.z + wz[4 * j + 3] * v.w;
          }
        }
      } else {
        for (int b = 0; b < BB; b++) {
          const float* xb = x + (((size_t)b * 128 + i0) * HH + rr) * WW + wcol;
#pragma unroll
          for (int j = 0; j < 32; j++) {
            acc[rl][b] += wz[j] * xb[(size_t)j * HH * WW];
          }
        }
      }
    }
  }

#pragma unroll
  for (int rl = 0; rl < 2; rl++)
#pragma unroll
    for (int b = 0; b < BB; b++) zred[rl * 8 + b][k4][o_loc] = acc[rl][b];
  __syncthreads();

  {
    int u = tid >> 4;
    int cell = tid & 15;
    int rl = cell >> 3;
    int b = cell & 7;
    int rr = r0 + rl;
    float z[4];
#pragma unroll
    for (int gg = 0; gg < 4; gg++) {
      int ol = gg * 16 + u;
      float s = zred[cell][0][ol] + zred[cell][1][ol] + zred[cell][2][ol] +
                zred[cell][3][ol];
      int Og = gg * 128 + q * 16 + u;
      z[gg] = s + b_is[Og] + b_ss[Og];
    }
    float iv = 1.0f / (1.0f + expf(-z[0]));
    float fv = 1.0f / (1.0f + expf(-z[1]));
    float ov = 1.0f / (1.0f + expf(-z[2]));
    float gv = tanhf(z[3]);
    int U = q * 16 + u;
    size_t sidx = ((size_t)b * HH + rr) * HID + U;
    float cv = c_state[sidx];
    float cn = fv * cv + iv * gv;
    c_state[sidx] = cn;
    float hn = ov * tanhf(cn);
    h_next[sidx] = hn;
    int wcol = t - rr;
    if (wcol >= 0 && wcol < WW) {
      out[(((size_t)b * HID + U) * HH + rr) * WW + wcol] = hn;
    }
  }
}

extern "C" void kernel_launch(void* const* d_in, const int* in_sizes, int n_in,
                              void* d_out, int out_size, void* d_ws,
                              size_t ws_size, hipStream_t stream) {
  const float* x = (const float*)d_in[0];
  const float* w_is = (const float*)d_in[1];
  const float* b_is = (const float*)d_in[2];
  const float* w_ss = (const float*)d_in[3];
  const float* b_ss = (const float*)d_in[4];
  float* outp = (float*)d_out;

  // zph has one extra 512-half bias slot at pos = B*H*W
  const size_t zph_bytes = ((size_t)BB * HH * WW * 512 + 512) * 2;
  const size_t wp_bytes = (size_t)512 * 256 * 2;    // 256 KiB
  const size_t wisa_bytes = (size_t)512 * 128 * 2;  // 128 KiB
  const size_t hx_bytes = (size_t)TT * 8 * 4 * 64 * 8;
  const size_t bsum_bytes = 512 * sizeof(float);
  const size_t need = zph_bytes + wp_bytes + wisa_bytes + hx_bytes + bsum_bytes;

  char* ws = (char*)d_ws;
  if (ws_size >= need) {
    __half* zph = (__half*)ws;
    _Float16* wpp = (_Float16*)(ws + zph_bytes);
    _Float16* wisa = (_Float16*)(ws + zph_bytes + wp_bytes);
    unsigned long long* hx =
        (unsigned long long*)(ws + zph_bytes + wp_bytes + wisa_bytes);
    float* bsum512 =
        (float*)(ws + zph_bytes + wp_bytes + wisa_bytes + hx_bytes);

    // prep covers 131072+65536+512+512+130048 = 327680 items -> 1280 blocks
    prep_w2<<<dim3(1280), 256, 0, stream>>>(w_ss, w_is, b_is, b_ss, wpp, wisa,
                                            zph, bsum512, hx);
    zpre_mfma<<<dim3(BB * HH), 256, 0, stream>>>(x, wisa, bsum512, zph);
    lstm_mfma<<<dim3(32), 512, 0, stream>>>(zph, wpp, hx, outp);
  } else {
    // -------- round-1 fallback --------
    const size_t xT_elems = (size_t)BB * HH * WW * 128;
    const size_t st_elems = (size_t)BB * HH * HID;
    const size_t need_xT = (xT_elems + 3 * st_elems) * sizeof(float);
    float* wsf = (float*)d_ws;
    float* xT = nullptr;
    float* st;
    int use_xT = 0;
    if (ws_size >= need_xT) {
      use_xT = 1;
      xT = wsf;
      st = wsf + xT_elems;
    } else {
      st = wsf;
    }
    float* h0 = st;
    float* h1 = st + st_elems;
    float* cb = st + 2 * st_elems;
    hipMemsetAsync(st, 0, 3 * st_elems * sizeof(float), stream);
    if (use_xT) transpose_x<<<dim3(BB * HH), 256, 0, stream>>>(x, xT);
    for (int t = 0; t < TT; t++) {
      float* hp = (t & 1) ? h1 : h0;
      float* hn = (t & 1) ? h0 : h1;
      step_kernel<<<dim3(32, 8), 256, 0, stream>>>(x, xT, use_xT, w_is, b_is,
                                                   w_ss, b_ss, hp, hn, cb, outp,
                                                   t);
    }
  }
}

// Round 2
// 321.393 us; speedup vs baseline: 1.0502x; 1.0294x over previous
//
#include <hip/hip_runtime.h>
#include <hip/hip_fp16.h>
#include <math.h>

// DiagonalLSTM: B=8, Cin=HID=128, H=64, W=64, K=2, T = 2W-1 = 127 steps.
//
// Round 16 design (round 15 + serial-chain cuts in the step body):
//   - MFMA accumulation split into two independent 4-link chains (kt 0-3 ->
//     acc0, kt 4-7 -> acc1, single f32 add at the end): halves the dependent
//     MFMA chain depth on the step critical path.
//   - chain-0's 4 ds_reads issued immediately after the barrier (before the
//     boundary-load issue / zf convert / zp prefetch), hiding first-use LDS
//     latency under that work; chain-1 reads stay inline and hide under
//     chain-0's MFMAs (also caps VGPR growth).
//   - t-loop unrolled 2x with compile-time rb/wb (126 = 63x2 + epilogue):
//     static LDS buffer bases, no per-step buffer-index arithmetic.
//   - otherwise the proven R10-R15 loop: 32 blocks x 512 thr, LDS-only step
//     barrier (no vmcnt drain), sentinel hx exchange (fire-and-forget),
//     1 barrier/step, boundary+zp prefetched 1 step ahead, bias folded into
//     zph, incremental pointers, reg-buffered out stores, clamp-free
//     fsig/ftanh.

#define HID 128
#define BB 8
#define HH 64
#define WW 64
#define TT 127

typedef _Float16 v8h __attribute__((ext_vector_type(8)));
typedef float v4f __attribute__((ext_vector_type(4)));

#define SENT64 0xFFFFFFFFFFFFFFFFULL  // 4x f16 -NaN (0xFF fill pattern)

__device__ __forceinline__ float fsig(float x) {
  // saturates correctly at +/-inf without clamping; never NaN
  float e = __builtin_amdgcn_exp2f(x * -1.44269504f);
  return __builtin_amdgcn_rcpf(1.f + e);
}
__device__ __forceinline__ float ftanh_(float x) {
  // 1 - 2/(1+exp2(2x*log2e)): NaN-free at +/-inf (unlike (e-1)/(e+1))
  float e = __builtin_amdgcn_exp2f(x * 2.88539009f);
  return __builtin_fmaf(-2.f, __builtin_amdgcn_rcpf(1.f + e), 1.f);
}

// ---- prep_w2: w_ss frags + w_is frags + zph bias slot + bsum + hx fill ----
__global__ __launch_bounds__(256) void prep_w2(const float* __restrict__ w_ss,
                                               const float* __restrict__ w_is,
                                               const float* __restrict__ b_is,
                                               const float* __restrict__ b_ss,
                                               _Float16* __restrict__ wp,
                                               _Float16* __restrict__ wisa,
                                               __half* __restrict__ zph,
                                               float* __restrict__ bsum512,
                                               unsigned long long* __restrict__ hx) {
  int idx = blockIdx.x * 256 + threadIdx.x;
  if (idx < 131072) {
    // w_ss -> Wcat(512x256) A-frags: wp[(((mt*8+kt)*64+L)*8+j)]
    int j = idx & 7;
    int L = (idx >> 3) & 63;
    int kt = (idx >> 9) & 7;
    int mt = idx >> 12;  // 0..31
    int O = mt * 16 + (L & 15);
    int k = kt * 32 + ((L >> 4) & 3) * 8 + j;
    float v = (k < 128) ? w_ss[(size_t)O * 256 + k * 2]
                        : w_ss[(size_t)O * 256 + (k - 128) * 2 + 1];
    wp[idx] = (_Float16)v;
  } else if (idx < 196608) {
    // w_is (512x128) A-frags: wisa[(((mt*4+kt)*64+L)*8+j)]
    int i2 = idx - 131072;
    int j = i2 & 7;
    int L = (i2 >> 3) & 63;
    int kt = (i2 >> 9) & 3;
    int mt = i2 >> 11;  // 0..31
    int O = mt * 16 + (L & 15);
    int k = kt * 32 + ((L >> 4) & 3) * 8 + j;
    wisa[i2] = (_Float16)w_is[(size_t)O * 128 + k];
  } else if (idx < 197120) {
    // zph bias slot: layout idx2 = (u>>2)*16 + g*4 + (u&3)
    int idx2 = idx - 196608;  // 0..511
    int g = (idx2 >> 2) & 3;
    int u = (idx2 >> 4) * 4 + (idx2 & 3);
    int O = g * 128 + u;
    zph[(size_t)BB * HH * WW * 512 + idx2] = __float2half(b_is[O] + b_ss[O]);
  } else if (idx < 197632) {
    int O = idx - 197120;
    bsum512[O] = b_is[O] + b_ss[O];
  } else if (idx < 197632 + 130048) {
    // hx sentinel fill: 260096 u64 as 130048 x 16B
    int j = idx - 197632;
    uint4 s;
    s.x = 0xFFFFFFFFu;
    s.y = 0xFFFFFFFFu;
    s.z = 0xFFFFFFFFu;
    s.w = 0xFFFFFFFFu;
    ((uint4*)hx)[j] = s;
  }
}

// ---- zpre_mfma: zph[pos*512 + (u>>2)*16 + g*4 + (u&3)] = z + bias ----
__global__ __launch_bounds__(256) void zpre_mfma(const float* __restrict__ x,
                                                 const _Float16* __restrict__ wisa,
                                                 const float* __restrict__ bsum512,
                                                 __half* __restrict__ zph) {
  const int b = blockIdx.x >> 6;
  const int r = blockIdx.x & 63;
  const int tid = threadIdx.x;
  const int wv = tid >> 6;  // 0..3 -> ntile
  const int L = tid & 63;
  const int quad = L >> 4;
  const int l15 = L & 15;

  __shared__ _Float16 xt[64][136];  // [w][c] f16, padded
  __shared__ float bs[512];

  if (tid < 128) {
    *(float4*)&bs[tid * 4] = *(const float4*)&bsum512[tid * 4];
  }
  // stage x(b,:,r,:) -> xt transposed; coalesced 16-lane c-row reads
  {
    const int cw = tid >> 4;        // c within pass
    const int w4 = (tid & 15) * 4;  // w base
#pragma unroll
    for (int p = 0; p < 8; p++) {
      int c = p * 16 + cw;
      float4 v = *(const float4*)&x[(((size_t)b * 128 + c) * HH + r) * WW + w4];
      xt[w4 + 0][c] = (_Float16)v.x;
      xt[w4 + 1][c] = (_Float16)v.y;
      xt[w4 + 2][c] = (_Float16)v.z;
      xt[w4 + 3][c] = (_Float16)v.w;
    }
  }
  __syncthreads();

  const int wcol = wv * 16 + l15;  // B-side n
  v8h bf[4];
#pragma unroll
  for (int kt = 0; kt < 4; kt++)
    bf[kt] = *(const v8h*)&xt[wcol][kt * 32 + quad * 8];

  const size_t pos = ((size_t)b * HH + r) * WW + wcol;
  const v8h* wa8 = (const v8h*)wisa;

#pragma unroll 4
  for (int mt = 0; mt < 32; mt++) {
    v4f acc = (v4f){0.f, 0.f, 0.f, 0.f};
#pragma unroll
    for (int kt = 0; kt < 4; kt++) {
      v8h af = wa8[((size_t)mt * 4 + kt) * 64 + L];
      acc = __builtin_amdgcn_mfma_f32_16x16x32_f16(af, bf[kt], acc, 0, 0, 0);
    }
    // O = mt*16 + quad*4 + reg; add bias, pack, store
    float4 bv = *(float4*)&bs[mt * 16 + quad * 4];
    __half2 lo = __floats2half2_rn(acc[0] + bv.x, acc[1] + bv.y);
    __half2 hi = __floats2half2_rn(acc[2] + bv.z, acc[3] + bv.w);
    uint2 pk;
    pk.x = *(unsigned*)&lo;
    pk.y = *(unsigned*)&hi;
    *(uint2*)&zph[pos * 512 + ((mt & 7) * 4 + quad) * 16 + (mt >> 3) * 4] = pk;
  }
}

// ---------------- persistent MFMA recurrent kernel -------------
#define HROW 136  // padded row stride in halfs

// Step barrier: LDS-visibility only (no vmcnt drain; see R15 notes).
#define STEP_BARRIER()                                   \
  do {                                                   \
    asm volatile("s_waitcnt lgkmcnt(0)" ::: "memory");   \
    __builtin_amdgcn_s_barrier();                        \
    asm volatile("" ::: "memory");                       \
  } while (0)

// One recurrence step with compile-time read-buffer index RB (write = RB^1).
// Phase order: chain-0 LDS reads first (hide first-use latency under the
// boundary-load issue + zf convert + zp prefetch), then two independent
// 4-link MFMA chains, then gates / exchange / export / out / validate.
#define STEP_BODY(T, RB)                                                       \
  do {                                                                         \
    /* phase 0: chain-0 LDS reads (slot rl) issued ASAP after barrier */       \
    v8h bfr[4];                                                                \
    _Pragma("unroll") for (int kt = 0; kt < 4; kt++)                           \
        bfr[kt] = *(const v8h*)&h_lds[RB][(rl * 2 + bl) * HROW + kt * 32 +     \
                                          quad * 8];                           \
    /* issue next boundary load (hx[T+1], consumed end of T+1) */              \
    unsigned long long newp = 0ull;                                            \
    if (is_cons && (T) + 1 < TT)                                               \
      newp = __hip_atomic_load(ca + 2048, __ATOMIC_RELAXED,                    \
                               __HIP_MEMORY_SCOPE_AGENT);                      \
    /* convert zu -> float (covers LDS latency; co-issues under MFMA) */       \
    float zf[16];                                                              \
    _Pragma("unroll") for (int i = 0; i < 16; i++)                             \
        zf[i] = __half2float(zu.h[i]);                                         \
    /* zp prefetch for T+1 (contiguous 32B; bias slot when out-of-band) */     \
    {                                                                          \
      const uint4* p = (const uint4*)(((unsigned)wn < WW) ? zcur : zbias);     \
      zu.q[0] = p[0];                                                          \
      zu.q[1] = p[1];                                                          \
      wn++;                                                                    \
      zcur += 512;                                                             \
    }                                                                          \
    /* MFMA: two independent 4-link chains (halved dependent depth) */         \
    v4f acc0[4], acc1[4];                                                      \
    _Pragma("unroll") for (int g = 0; g < 4; g++) {                            \
      acc0[g] = (v4f){0.f, 0.f, 0.f, 0.f};                                     \
      acc1[g] = (v4f){0.f, 0.f, 0.f, 0.f};                                     \
    }                                                                          \
    _Pragma("unroll") for (int kt = 0; kt < 4; kt++) {                         \
      _Pragma("unroll") for (int g = 0; g < 4; g++)                            \
          acc0[g] = __builtin_amdgcn_mfma_f32_16x16x32_f16(                    \
              wfrag[g][kt], bfr[kt], acc0[g], 0, 0, 0);                        \
    }                                                                          \
    _Pragma("unroll") for (int kt = 0; kt < 4; kt++) {                         \
      v8h bf1 = *(const v8h*)&h_lds[RB][((rl + 1) * 2 + bl) * HROW + kt * 32 + \
                                        quad * 8];                             \
      _Pragma("unroll") for (int g = 0; g < 4; g++)                            \
          acc1[g] = __builtin_amdgcn_mfma_f32_16x16x32_f16(                    \
              wfrag[g][4 + kt], bf1, acc1[g], 0, 0, 0);                        \
    }                                                                          \
    /* gates (bias pre-folded into zph/zf) */                                  \
    const int w = (T)-r;                                                       \
    const bool inband = ((unsigned)w < WW);                                    \
    float hv[4];                                                               \
    _Pragma("unroll") for (int rg2 = 0; rg2 < 4; rg2++) {                      \
      float z0 = (acc0[0][rg2] + acc1[0][rg2]) + zf[0 * 4 + rg2];              \
      float z1 = (acc0[1][rg2] + acc1[1][rg2]) + zf[1 * 4 + rg2];              \
      float z2 = (acc0[2][rg2] + acc1[2][rg2]) + zf[2 * 4 + rg2];              \
      float z3 = (acc0[3][rg2] + acc1[3][rg2]) + zf[3 * 4 + rg2];              \
      float iv = fsig(z0);                                                     \
      float fv = fsig(z1);                                                     \
      float ov = fsig(z2);                                                     \
      float gv = ftanh_(z3);                                                   \
      c[rg2] = fv * c[rg2] + iv * gv;                                          \
      hv[rg2] = ov * ftanh_(c[rg2]);                                           \
    }                                                                          \
    /* h(T) -> write-buffer slots 1..8 (LDS, 8B per lane) */                   \
    __half2 plo = __floats2half2_rn(hv[0], hv[1]);                             \
    __half2 phi = __floats2half2_rn(hv[2], hv[3]);                             \
    {                                                                          \
      uint2 pk;                                                                \
      pk.x = *(unsigned*)&plo;                                                 \
      pk.y = *(unsigned*)&phi;                                                 \
      *(uint2*)&h_lds[(RB) ^ 1][((rl + 1) * 2 + bl) * HROW + uq0] = pk;        \
    }                                                                          \
    /* export h(T)[R0+7]: fire-and-forget (data == flag, no drain) */          \
    if (rgr < 7 && l15 >= 14) {                                                \
      unsigned long long pk =                                                  \
          ((unsigned long long)*(unsigned*)&phi << 32) | *(unsigned*)&plo;     \
      __hip_atomic_store(pa, pk, __ATOMIC_RELAXED, __HIP_MEMORY_SCOPE_AGENT);  \
    }                                                                          \
    pa += 2048;                                                                \
    /* out shift-window; coalesced 16B flush every 4 steps per cell */         \
    _Pragma("unroll") for (int rg2 = 0; rg2 < 4; rg2++) {                      \
      outb[rg2].x = outb[rg2].y;                                               \
      outb[rg2].y = outb[rg2].z;                                               \
      outb[rg2].z = outb[rg2].w;                                               \
      outb[rg2].w = hv[rg2];                                                   \
    }                                                                          \
    if (inband && (w & 3) == 3) {                                              \
      *(float4*)op0 = outb[0];                                                 \
      *(float4*)op1 = outb[1];                                                 \
      *(float4*)op2 = outb[2];                                                 \
      *(float4*)op3 = outb[3];                                                 \
      op0 += 4;                                                                \
      op1 += 4;                                                                \
      op2 += 4;                                                                \
      op3 += 4;                                                                \
    }                                                                          \
    /* validate pend (hx[T] = h(T)[R0-1]); last = spin overlaps tail work */   \
    if (is_cons) {                                                             \
      while (__ballot(pend == SENT64) != 0ull) {                               \
        __builtin_amdgcn_s_sleep(1);                                           \
        pend = __hip_atomic_load(ca, __ATOMIC_RELAXED,                         \
                                 __HIP_MEMORY_SCOPE_AGENT);                    \
      }                                                                        \
      *(unsigned long long*)&h_lds[(RB) ^ 1][(0 * 2 + ebl) * HROW + eu] =      \
          pend;                                                                \
      pend = newp;                                                             \
    }                                                                          \
    ca += 2048;                                                                \
    STEP_BARRIER();                                                            \
  } while (0)

__global__ __launch_bounds__(512, 1) void lstm_mfma(
    const __half* __restrict__ zph, const _Float16* __restrict__ wp,
    unsigned long long* __restrict__ hx,  // [TT][8][4][64], sentinel-filled
    float* __restrict__ out) {
  const int blk = blockIdx.x;  // 0..31
  const int rgr = blk >> 2;    // row group 0..7 (rows 8*rgr .. +7)
  const int bg = blk & 3;      // batch group 0..3 (b = 2*bg, 2*bg+1)
  const int R0 = rgr * 8;
  const int tid = threadIdx.x;
  const int wv = tid >> 6;  // wave 0..7
  const int L = tid & 63;
  const int quad = L >> 4;
  const int l15 = L & 15;
  const int rl = l15 >> 1;  // cell row-local 0..7
  const int bl = l15 & 1;   // cell batch-local 0..1
  const int b = bg * 2 + bl;
  const int r = R0 + rl;
  const int uq0 = 16 * wv + quad * 4;     // D-side unit base (+reg)
  const int zoff = (4 * wv + quad) * 16;  // zp contiguous 16-half group

  // double-buffered: slot s holds row R0-1+s (s=0..8), per b-local
  __shared__ _Float16 h_lds[2][9 * 2 * HROW];
  for (int i = tid; i < (2 * 9 * 2 * HROW) / 2; i += 512)
    ((unsigned*)h_lds)[i] = 0u;

  // ---- weights as A-fragments, loaded once ----
  v8h wfrag[4][8];
  {
    const v8h* wp8 = (const v8h*)wp;
#pragma unroll
    for (int g = 0; g < 4; g++)
#pragma unroll
      for (int kt = 0; kt < 8; kt++)
        wfrag[g][kt] = wp8[((size_t)((8 * g + wv) * 8 + kt)) * 64 + L];
  }

  float c[4] = {0.f, 0.f, 0.f, 0.f};
  float4 outb[4];  // shift-window out buffer (w-3..w per cell)
#pragma unroll
  for (int i = 0; i < 4; i++) outb[i] = make_float4(0.f, 0.f, 0.f, 0.f);

  const int ebl = L >> 5;       // boundary consumer: b-local
  const int eu = (L & 31) * 4;  // boundary consumer: unit base
  const int exp_idx = bl * 32 + 4 * wv + quad;  // producer slot (l15>=14)

  const bool is_cons = (wv == 0) && (rgr > 0);

  // ---- incremental pointers ----
  const __half* zpp = zph + ((size_t)b * HH + r) * WW * 512 + zoff;
  const __half* zbias = zph + (size_t)BB * HH * WW * 512 + zoff;
  const unsigned long long* ca =
      hx + (((size_t)(rgr > 0 ? rgr - 1 : 0) * 4 + bg) * 64 + L);  // hx[t]
  unsigned long long* pa = hx + (((size_t)rgr * 4 + bg) * 64 + exp_idx);
  float* op0 = out + (((size_t)b * HID + uq0 + 0) * HH + r) * WW;
  float* op1 = out + (((size_t)b * HID + uq0 + 1) * HH + r) * WW;
  float* op2 = out + (((size_t)b * HID + uq0 + 2) * HH + r) * WW;
  float* op3 = out + (((size_t)b * HID + uq0 + 3) * HH + r) * WW;

  // ---- zp for t=0 (w0 = -r: in-band only for r==0) ----
  union ZU {
    uint4 q[2];
    __half h[16];  // h[g*4 + rg2]
  } zu;
  {
    const uint4* p0 = (const uint4*)((r == 0) ? zpp : zbias);
    zu.q[0] = p0[0];
    zu.q[1] = p0[1];
  }
  int wn = 1 - r;  // next-step w
  const __half* zcur = zpp + (ptrdiff_t)wn * 512;

  // ---- boundary pipeline: pend = load of hx[t=0] ----
  unsigned long long pend = 0ull;
  if (is_cons) {
    pend = __hip_atomic_load(ca, __ATOMIC_RELAXED, __HIP_MEMORY_SCOPE_AGENT);
  }

  __syncthreads();

  // 126 = 63x2 steps with static read-buffer index, then epilogue t=126.
  for (int t = 0; t < TT - 1; t += 2) {
    STEP_BODY(t, 0);
    STEP_BODY(t + 1, 1);
  }
  STEP_BODY(TT - 1, 0);
}

// ================= round-1 fallback path (proven correct) =================
__global__ __launch_bounds__(256) void transpose_x(const float* __restrict__ x,
                                                   float* __restrict__ xT) {
  int b = blockIdx.x >> 6;
  int r = blockIdx.x & 63;
  __shared__ float tile[32][65];
  for (int cc = 0; cc < 4; cc++) {
    int cl = threadIdx.x >> 6;
    int w = threadIdx.x & 63;
#pragma unroll
    for (int k = 0; k < 8; k++) {
      int c_loc = k * 4 + cl;
      int c = cc * 32 + c_loc;
      tile[c_loc][w] = x[(((size_t)b * 128 + c) * HH + r) * WW + w];
    }
    __syncthreads();
    int cs = threadIdx.x & 31;
    int wp = threadIdx.x >> 5;
#pragma unroll
    for (int k = 0; k < 8; k++) {
      int w2 = wp * 8 + k;
      xT[(((size_t)b * HH + r) * WW + w2) * 128 + cc * 32 + cs] = tile[cs][w2];
    }
    __syncthreads();
  }
}

__global__ __launch_bounds__(256) void step_kernel(
    const float* __restrict__ x, const float* __restrict__ xT, int use_xT,
    const float* __restrict__ w_is, const float* __restrict__ b_is,
    const float* __restrict__ w_ss, const float* __restrict__ b_ss,
    const float* __restrict__ h_prev, float* __restrict__ h_next,
    float* __restrict__ c_state, float* __restrict__ out, int t) {
  const int rg = blockIdx.x;
  const int q = blockIdx.y;
  const int r0 = rg * 2;
  const int tid = threadIdx.x;
  const int o_loc = tid & 63;
  const int k4 = tid >> 6;
  const int g_ = o_loc >> 4;
  const int u_ = o_loc & 15;
  const int O = g_ * 128 + q * 16 + u_;
  const int i0 = k4 * 32;

  __shared__ __align__(16) float h_in[3][BB][HID];
  __shared__ float zred[16][4][65];

  for (int idx = tid; idx < 3 * BB * HID; idx += 256) {
    int row_sel = idx >> 10;
    int rem = idx & 1023;
    int b = rem >> 7;
    int u = rem & 127;
    int rr = r0 - 1 + row_sel;
    h_in[row_sel][b][u] = (rr >= 0) ? h_prev[((size_t)b * HH + rr) * HID + u] : 0.0f;
  }

  float wr0[32], wr1[32], wz[32];
  {
    const float4* wss4 = (const float4*)(w_ss + ((size_t)O * 128 + i0) * 2);
#pragma unroll
    for (int j = 0; j < 16; j++) {
      float4 v = wss4[j];
      wr0[2 * j] = v.x;
      wr1[2 * j] = v.y;
      wr0[2 * j + 1] = v.z;
      wr1[2 * j + 1] = v.w;
    }
    const float4* wis4 = (const float4*)(w_is + (size_t)O * 128 + i0);
#pragma unroll
    for (int j = 0; j < 8; j++) {
      float4 v = wis4[j];
      wz[4 * j] = v.x;
      wz[4 * j + 1] = v.y;
      wz[4 * j + 2] = v.z;
      wz[4 * j + 3] = v.w;
    }
  }

  __syncthreads();

  float acc[2][BB];
#pragma unroll
  for (int rl = 0; rl < 2; rl++)
#pragma unroll
    for (int b = 0; b < BB; b++) acc[rl][b] = 0.0f;

#pragma unroll
  for (int jb = 0; jb < 8; jb++) {
    int ib = i0 + jb * 4;
#pragma unroll
    for (int b = 0; b < BB; b++) {
      const float4 hm4 = *(const float4*)&h_in[0][b][ib];
      const float4 hc4 = *(const float4*)&h_in[1][b][ib];
      const float4 hp4 = *(const float4*)&h_in[2][b][ib];
      const float* hm = (const float*)&hm4;
      const float* hc = (const float*)&hc4;
      const float* hq = (const float*)&hp4;
#pragma unroll
      for (int jj = 0; jj < 4; jj++) {
        float w0v = wr0[jb * 4 + jj];
        float w1v = wr1[jb * 4 + jj];
        acc[0][b] += w0v * hm[jj] + w1v * hc[jj];
        acc[1][b] += w0v * hc[jj] + w1v * hq[jj];
      }
    }
  }

#pragma unroll
  for (int rl = 0; rl < 2; rl++) {
    int rr = r0 + rl;
    int wcol = t - rr;
    if (wcol >= 0 && wcol < WW) {
      if (use_xT) {
        for (int b = 0; b < BB; b++) {
          const float4* xp =
              (const float4*)(xT + (((size_t)b * HH + rr) * WW + wcol) * 128 + i0);
#pragma unroll
          for (int j = 0; j < 8; j++) {
            float4 v = xp[j];
            acc[rl][b] += wz[4 * j] * v.x + wz[4 * j + 1] * v.y +
                          wz[4 * j + 2] * v.z + wz[4 * j + 3] * v.w;
          }
        }
      } else {
        for (int b = 0; b < BB; b++) {
          const float* xb = x + (((size_t)b * 128 + i0) * HH + rr) * WW + wcol;
#pragma unroll
          for (int j = 0; j < 32; j++) {
            acc[rl][b] += wz[j] * xb[(size_t)j * HH * WW];
          }
        }
      }
    }
  }

#pragma unroll
  for (int rl = 0; rl < 2; rl++)
#pragma unroll
    for (int b = 0; b < BB; b++) zred[rl * 8 + b][k4][o_loc] = acc[rl][b];
  __syncthreads();

  {
    int u = tid >> 4;
    int cell = tid & 15;
    int rl = cell >> 3;
    int b = cell & 7;
    int rr = r0 + rl;
    float z[4];
#pragma unroll
    for (int gg = 0; gg < 4; gg++) {
      int ol = gg * 16 + u;
      float s = zred[cell][0][ol] + zred[cell][1][ol] + zred[cell][2][ol] +
                zred[cell][3][ol];
      int Og = gg * 128 + q * 16 + u;
      z[gg] = s + b_is[Og] + b_ss[Og];
    }
    float iv = 1.0f / (1.0f + expf(-z[0]));
    float fv = 1.0f / (1.0f + expf(-z[1]));
    float ov = 1.0f / (1.0f + expf(-z[2]));
    float gv = tanhf(z[3]);
    int U = q * 16 + u;
    size_t sidx = ((size_t)b * HH + rr) * HID + U;
    float cv = c_state[sidx];
    float cn = fv * cv + iv * gv;
    c_state[sidx] = cn;
    float hn = ov * tanhf(cn);
    h_next[sidx] = hn;
    int wcol = t - rr;
    if (wcol >= 0 && wcol < WW) {
      out[(((size_t)b * HID + U) * HH + rr) * WW + wcol] = hn;
    }
  }
}

extern "C" void kernel_launch(void* const* d_in, const int* in_sizes, int n_in,
                              void* d_out, int out_size, void* d_ws,
                              size_t ws_size, hipStream_t stream) {
  const float* x = (const float*)d_in[0];
  const float* w_is = (const float*)d_in[1];
  const float* b_is = (const float*)d_in[2];
  const float* w_ss = (const float*)d_in[3];
  const float* b_ss = (const float*)d_in[4];
  float* outp = (float*)d_out;

  // zph has one extra 512-half bias slot at pos = B*H*W
  const size_t zph_bytes = ((size_t)BB * HH * WW * 512 + 512) * 2;
  const size_t wp_bytes = (size_t)512 * 256 * 2;    // 256 KiB
  const size_t wisa_bytes = (size_t)512 * 128 * 2;  // 128 KiB
  const size_t hx_bytes = (size_t)TT * 8 * 4 * 64 * 8;
  const size_t bsum_bytes = 512 * sizeof(float);
  const size_t need = zph_bytes + wp_bytes + wisa_bytes + hx_bytes + bsum_bytes;

  char* ws = (char*)d_ws;
  if (ws_size >= need) {
    __half* zph = (__half*)ws;
    _Float16* wpp = (_Float16*)(ws + zph_bytes);
    _Float16* wisa = (_Float16*)(ws + zph_bytes + wp_bytes);
    unsigned long long* hx =
        (unsigned long long*)(ws + zph_bytes + wp_bytes + wisa_bytes);
    float* bsum512 =
        (float*)(ws + zph_bytes + wp_bytes + wisa_bytes + hx_bytes);

    // prep covers 131072+65536+512+512+130048 = 327680 items -> 1280 blocks
    prep_w2<<<dim3(1280), 256, 0, stream>>>(w_ss, w_is, b_is, b_ss, wpp, wisa,
                                            zph, bsum512, hx);
    zpre_mfma<<<dim3(BB * HH), 256, 0, stream>>>(x, wisa, bsum512, zph);
    lstm_mfma<<<dim3(32), 512, 0, stream>>>(zph, wpp, hx, outp);
  } else {
    // -------- round-1 fallback --------
    const size_t xT_elems = (size_t)BB * HH * WW * 128;
    const size_t st_elems = (size_t)BB * HH * HID;
    const size_t need_xT = (xT_elems + 3 * st_elems) * sizeof(float);
    float* wsf = (float*)d_ws;
    float* xT = nullptr;
    float* st;
    int use_xT = 0;
    if (ws_size >= need_xT) {
      use_xT = 1;
      xT = wsf;
      st = wsf + xT_elems;
    } else {
      st = wsf;
    }
    float* h0 = st;
    float* h1 = st + st_elems;
    float* cb = st + 2 * st_elems;
    hipMemsetAsync(st, 0, 3 * st_elems * sizeof(float), stream);
    if (use_xT) transpose_x<<<dim3(BB * HH), 256, 0, stream>>>(x, xT);
    for (int t = 0; t < TT; t++) {
      float* hp = (t & 1) ? h1 : h0;
      float* hn = (t & 1) ? h0 : h1;
      step_kernel<<<dim3(32, 8), 256, 0, stream>>>(x, xT, use_xT, w_is, b_is,
                                                   w_ss, b_ss, hp, hn, cb, outp,
                                                   t);
    }
  }
}

// Round 4
// 313.863 us; speedup vs baseline: 1.0754x; 1.0240x over previous
//
#include <hip/hip_runtime.h>
#include <hip/hip_fp16.h>
#include <math.h>

// DiagonalLSTM: B=8, Cin=HID=128, H=64, W=64, K=2, T = 2W-1 = 127 steps.
//
// Round 18 = Round 17 resubmitted verbatim (R17 bench was an infra failure:
// "MI355X container failed twice", no pytest/profile output; audit found no
// hang vector -- prep_zpre has no spins and uniform branching, lstm_mfma's
// sync structure is byte-identical to the R16 kernel that passed).
//
// Round 17 design (round 16 + kernel merge + z-via-C-operand):
//   - prep_w2 + zpre_mfma merged into ONE kernel (3 launches -> 2): the
//     zpre half no longer needs prep's wisa/bsum512 -- each zpre wave
//     converts its own w_is A-fragments once into registers (8 mt-tiles
//     x 4 kt = 32 v8h, A register-resident) and computes bias inline.
//     This also kills zpre's old inner loop re-reading 128x16B of wisa
//     from global per thread.
//   - lstm: z enters through the MFMA C-operand (acc1 initialized with the
//     converted z instead of 0) -> 16 fewer f32 adds per thread per step.
//   - otherwise the proven R10-R16 loop: 32 blocks x 512 thr, LDS-only step
//     barrier (no vmcnt drain), two independent 4-link MFMA chains, chain-0
//     ds_reads issued right after the barrier, 2x-unrolled t-loop with
//     static buffer indices, sentinel hx exchange (fire-and-forget),
//     boundary+zp prefetched 1 step ahead, bias folded into zph,
//     incremental pointers, reg-buffered out stores, clamp-free fsig/ftanh.

#define HID 128
#define BB 8
#define HH 64
#define WW 64
#define TT 127

// prep item counts: 131072 (wp frags) + 512 (zph bias) + 130048 (hx fill)
//                 = 261632 = 1022 * 256 exactly
#define NPREP 1022

typedef _Float16 v8h __attribute__((ext_vector_type(8)));
typedef float v4f __attribute__((ext_vector_type(4)));

#define SENT64 0xFFFFFFFFFFFFFFFFULL  // 4x f16 -NaN (0xFF fill pattern)

__device__ __forceinline__ float fsig(float x) {
  // saturates correctly at +/-inf without clamping; never NaN
  float e = __builtin_amdgcn_exp2f(x * -1.44269504f);
  return __builtin_amdgcn_rcpf(1.f + e);
}
__device__ __forceinline__ float ftanh_(float x) {
  // 1 - 2/(1+exp2(2x*log2e)): NaN-free at +/-inf (unlike (e-1)/(e+1))
  float e = __builtin_amdgcn_exp2f(x * 2.88539009f);
  return __builtin_fmaf(-2.f, __builtin_amdgcn_rcpf(1.f + e), 1.f);
}

// ---- merged prep + zpre kernel ----
// blocks [0, NPREP): prep items (wp frags, zph bias slot, hx sentinel fill)
// blocks [NPREP, NPREP+512): zpre for (b,r) = bid-NPREP
//   zpre is self-sufficient: converts w_is fragments into registers and
//   computes b_is+b_ss inline -> no dependency on the prep blocks.
__global__ __launch_bounds__(256) void prep_zpre(
    const float* __restrict__ x, const float* __restrict__ w_is,
    const float* __restrict__ b_is, const float* __restrict__ b_ss,
    const float* __restrict__ w_ss, _Float16* __restrict__ wp,
    __half* __restrict__ zph, unsigned long long* __restrict__ hx) {
  const int bid = blockIdx.x;
  const int tid = threadIdx.x;

  __shared__ _Float16 xt[64][136];  // [w][c] f16, padded (zpre half only)

  if (bid < NPREP) {
    int idx = bid * 256 + tid;
    if (idx < 131072) {
      // w_ss -> Wcat(512x256) A-frags: wp[(((mt*8+kt)*64+L)*8+j)]
      int j = idx & 7;
      int L = (idx >> 3) & 63;
      int kt = (idx >> 9) & 7;
      int mt = idx >> 12;  // 0..31
      int O = mt * 16 + (L & 15);
      int k = kt * 32 + ((L >> 4) & 3) * 8 + j;
      float v = (k < 128) ? w_ss[(size_t)O * 256 + k * 2]
                          : w_ss[(size_t)O * 256 + (k - 128) * 2 + 1];
      wp[idx] = (_Float16)v;
    } else if (idx < 131584) {
      // zph bias slot: layout idx2 = (u>>2)*16 + g*4 + (u&3)
      int idx2 = idx - 131072;  // 0..511
      int g = (idx2 >> 2) & 3;
      int u = (idx2 >> 4) * 4 + (idx2 & 3);
      int O = g * 128 + u;
      zph[(size_t)BB * HH * WW * 512 + idx2] = __float2half(b_is[O] + b_ss[O]);
    } else {
      // hx sentinel fill: 260096 u64 as 130048 x 16B
      int j = idx - 131584;
      uint4 s;
      s.x = 0xFFFFFFFFu;
      s.y = 0xFFFFFFFFu;
      s.z = 0xFFFFFFFFu;
      s.w = 0xFFFFFFFFu;
      ((uint4*)hx)[j] = s;
    }
    return;
  }

  // ---------------- zpre half ----------------
  const int zb = bid - NPREP;  // 0..511
  const int b = zb >> 6;
  const int r = zb & 63;
  const int wv = tid >> 6;  // 0..3 -> owns gate wv (mt = 8*wv + m)
  const int L = tid & 63;
  const int quad = L >> 4;
  const int l15 = L & 15;

  // stage x(b,:,r,:) -> xt transposed; coalesced 16-lane c-row reads
  {
    const int cw = tid >> 4;        // c within pass
    const int w4 = (tid & 15) * 4;  // w base
#pragma unroll
    for (int p = 0; p < 8; p++) {
      int c = p * 16 + cw;
      float4 v = *(const float4*)&x[(((size_t)b * 128 + c) * HH + r) * WW + w4];
      xt[w4 + 0][c] = (_Float16)v.x;
      xt[w4 + 1][c] = (_Float16)v.y;
      xt[w4 + 2][c] = (_Float16)v.z;
      xt[w4 + 3][c] = (_Float16)v.w;
    }
  }

  // wave-owned A-frags: convert w_is f32 -> v8h once (overlaps staging)
  // frag lane L, tile (mt,kt) holds w_is[O*128 + kt*32 + quad*8 + (0..7)],
  // O = mt*16 + l15  (identical mapping to the old wisa array)
  v8h wfr[8][4];
  float4 bv[8];
#pragma unroll
  for (int m = 0; m < 8; m++) {
    const int mt = 8 * wv + m;
    const int O = mt * 16 + l15;
#pragma unroll
    for (int kt = 0; kt < 4; kt++) {
      const float* p = w_is + (size_t)O * 128 + kt * 32 + quad * 8;
      float4 a = *(const float4*)p;
      float4 b2 = *(const float4*)(p + 4);
      v8h f;
      f[0] = (_Float16)a.x;
      f[1] = (_Float16)a.y;
      f[2] = (_Float16)a.z;
      f[3] = (_Float16)a.w;
      f[4] = (_Float16)b2.x;
      f[5] = (_Float16)b2.y;
      f[6] = (_Float16)b2.z;
      f[7] = (_Float16)b2.w;
      wfr[m][kt] = f;
    }
    const int O4 = mt * 16 + quad * 4;
    float4 bi = *(const float4*)&b_is[O4];
    float4 bs4 = *(const float4*)&b_ss[O4];
    bv[m] = make_float4(bi.x + bs4.x, bi.y + bs4.y, bi.z + bs4.z, bi.w + bs4.w);
  }

  __syncthreads();

  // 4 n-tiles (w groups of 16); A in regs, B from LDS
#pragma unroll
  for (int nt = 0; nt < 4; nt++) {
    v8h bf[4];
#pragma unroll
    for (int kt = 0; kt < 4; kt++)
      bf[kt] = *(const v8h*)&xt[nt * 16 + l15][kt * 32 + quad * 8];
    const size_t pos = ((size_t)b * HH + r) * WW + nt * 16 + l15;
#pragma unroll
    for (int m = 0; m < 8; m++) {
      v4f acc = (v4f){0.f, 0.f, 0.f, 0.f};
#pragma unroll
      for (int kt = 0; kt < 4; kt++)
        acc = __builtin_amdgcn_mfma_f32_16x16x32_f16(wfr[m][kt], bf[kt], acc,
                                                     0, 0, 0);
      const int mt = 8 * wv + m;  // mt&7 == m, mt>>3 == wv (gate index)
      __half2 lo = __floats2half2_rn(acc[0] + bv[m].x, acc[1] + bv[m].y);
      __half2 hi = __floats2half2_rn(acc[2] + bv[m].z, acc[3] + bv[m].w);
      uint2 pk;
      pk.x = *(unsigned*)&lo;
      pk.y = *(unsigned*)&hi;
      *(uint2*)&zph[pos * 512 + (m * 4 + quad) * 16 + wv * 4] = pk;
    }
  }
}

// ---------------- persistent MFMA recurrent kernel -------------
#define HROW 136  // padded row stride in halfs

// Step barrier: LDS-visibility only (no vmcnt drain; see R15 notes).
#define STEP_BARRIER()                                   \
  do {                                                   \
    asm volatile("s_waitcnt lgkmcnt(0)" ::: "memory");   \
    __builtin_amdgcn_s_barrier();                        \
    asm volatile("" ::: "memory");                       \
  } while (0)

// One recurrence step with compile-time read-buffer index RB (write = RB^1).
// Phase order: chain-0 LDS reads first, z conversion (feeds chain-1's
// C-operand init), boundary-load issue, zp prefetch, two independent 4-link
// MFMA chains (chain-1 carries z in its accumulator), gates with a single
// acc0+acc1 add, exchange / export / out / validate.
#define STEP_BODY(T, RB)                                                       \
  do {                                                                         \
    /* phase 0: chain-0 LDS reads (slot rl) issued ASAP after barrier */       \
    v8h bfr[4];                                                                \
    _Pragma("unroll") for (int kt = 0; kt < 4; kt++)                           \
        bfr[kt] = *(const v8h*)&h_lds[RB][(rl * 2 + bl) * HROW + kt * 32 +     \
                                          quad * 8];                           \
    /* convert zu -> v4f (chain-1 C-operand init; single use per value) */     \
    v4f zi[4];                                                                 \
    _Pragma("unroll") for (int g = 0; g < 4; g++)                              \
        _Pragma("unroll") for (int i = 0; i < 4; i++)                          \
        zi[g][i] = __half2float(zu.h[g * 4 + i]);                              \
    /* issue next boundary load (hx[T+1], consumed end of T+1) */              \
    unsigned long long newp = 0ull;                                            \
    if (is_cons && (T) + 1 < TT)                                               \
      newp = __hip_atomic_load(ca + 2048, __ATOMIC_RELAXED,                    \
                               __HIP_MEMORY_SCOPE_AGENT);                      \
    /* zp prefetch for T+1 (contiguous 32B; bias slot when out-of-band) */     \
    {                                                                          \
      const uint4* p = (const uint4*)(((unsigned)wn < WW) ? zcur : zbias);     \
      zu.q[0] = p[0];                                                          \
      zu.q[1] = p[1];                                                          \
      wn++;                                                                    \
      zcur += 512;                                                             \
    }                                                                          \
    /* MFMA: two independent 4-link chains; chain-1 accumulates onto z */      \
    v4f acc0[4], acc1[4];                                                      \
    _Pragma("unroll") for (int g = 0; g < 4; g++) {                            \
      acc0[g] = (v4f){0.f, 0.f, 0.f, 0.f};                                     \
      acc1[g] = zi[g];                                                         \
    }                                                                          \
    _Pragma("unroll") for (int kt = 0; kt < 4; kt++) {                         \
      _Pragma("unroll") for (int g = 0; g < 4; g++)                            \
          acc0[g] = __builtin_amdgcn_mfma_f32_16x16x32_f16(                    \
              wfrag[g][kt], bfr[kt], acc0[g], 0, 0, 0);                        \
    }                                                                          \
    _Pragma("unroll") for (int kt = 0; kt < 4; kt++) {                         \
      v8h bf1 = *(const v8h*)&h_lds[RB][((rl + 1) * 2 + bl) * HROW + kt * 32 + \
                                        quad * 8];                             \
      _Pragma("unroll") for (int g = 0; g < 4; g++)                            \
          acc1[g] = __builtin_amdgcn_mfma_f32_16x16x32_f16(                    \
              wfrag[g][4 + kt], bf1, acc1[g], 0, 0, 0);                        \
    }                                                                          \
    /* gates (bias pre-folded into zph -> rides in acc1) */                    \
    const int w = (T)-r;                                                       \
    const bool inband = ((unsigned)w < WW);                                    \
    float hv[4];                                                               \
    _Pragma("unroll") for (int rg2 = 0; rg2 < 4; rg2++) {                      \
      float z0 = acc0[0][rg2] + acc1[0][rg2];                                  \
      float z1 = acc0[1][rg2] + acc1[1][rg2];                                  \
      float z2 = acc0[2][rg2] + acc1[2][rg2];                                  \
      float z3 = acc0[3][rg2] + acc1[3][rg2];                                  \
      float iv = fsig(z0);                                                     \
      float fv = fsig(z1);                                                     \
      float ov = fsig(z2);                                                     \
      float gv = ftanh_(z3);                                                   \
      c[rg2] = fv * c[rg2] + iv * gv;                                          \
      hv[rg2] = ov * ftanh_(c[rg2]);                                           \
    }                                                                          \
    /* h(T) -> write-buffer slots 1..8 (LDS, 8B per lane) */                   \
    __half2 plo = __floats2half2_rn(hv[0], hv[1]);                             \
    __half2 phi = __floats2half2_rn(hv[2], hv[3]);                             \
    {                                                                          \
      uint2 pk;                                                                \
      pk.x = *(unsigned*)&plo;                                                 \
      pk.y = *(unsigned*)&phi;                                                 \
      *(uint2*)&h_lds[(RB) ^ 1][((rl + 1) * 2 + bl) * HROW + uq0] = pk;        \
    }                                                                          \
    /* export h(T)[R0+7]: fire-and-forget (data == flag, no drain) */          \
    if (rgr < 7 && l15 >= 14) {                                                \
      unsigned long long pk =                                                  \
          ((unsigned long long)*(unsigned*)&phi << 32) | *(unsigned*)&plo;     \
      __hip_atomic_store(pa, pk, __ATOMIC_RELAXED, __HIP_MEMORY_SCOPE_AGENT);  \
    }                                                                          \
    pa += 2048;                                                                \
    /* out shift-window; coalesced 16B flush every 4 steps per cell */         \
    _Pragma("unroll") for (int rg2 = 0; rg2 < 4; rg2++) {                      \
      outb[rg2].x = outb[rg2].y;                                               \
      outb[rg2].y = outb[rg2].z;                                               \
      outb[rg2].z = outb[rg2].w;                                               \
      outb[rg2].w = hv[rg2];                                                   \
    }                                                                          \
    if (inband && (w & 3) == 3) {                                              \
      *(float4*)op0 = outb[0];                                                 \
      *(float4*)op1 = outb[1];                                                 \
      *(float4*)op2 = outb[2];                                                 \
      *(float4*)op3 = outb[3];                                                 \
      op0 += 4;                                                                \
      op1 += 4;                                                                \
      op2 += 4;                                                                \
      op3 += 4;                                                                \
    }                                                                          \
    /* validate pend (hx[T] = h(T)[R0-1]); spin overlaps tail work */          \
    if (is_cons) {                                                             \
      while (__ballot(pend == SENT64) != 0ull) {                               \
        __builtin_amdgcn_s_sleep(1);                                           \
        pend = __hip_atomic_load(ca, __ATOMIC_RELAXED,                         \
                                 __HIP_MEMORY_SCOPE_AGENT);                    \
      }                                                                        \
      *(unsigned long long*)&h_lds[(RB) ^ 1][(0 * 2 + ebl) * HROW + eu] =      \
          pend;                                                                \
      pend = newp;                                                             \
    }                                                                          \
    ca += 2048;                                                                \
    STEP_BARRIER();                                                            \
  } while (0)

__global__ __launch_bounds__(512, 1) void lstm_mfma(
    const __half* __restrict__ zph, const _Float16* __restrict__ wp,
    unsigned long long* __restrict__ hx,  // [TT][8][4][64], sentinel-filled
    float* __restrict__ out) {
  const int blk = blockIdx.x;  // 0..31
  const int rgr = blk >> 2;    // row group 0..7 (rows 8*rgr .. +7)
  const int bg = blk & 3;      // batch group 0..3 (b = 2*bg, 2*bg+1)
  const int R0 = rgr * 8;
  const int tid = threadIdx.x;
  const int wv = tid >> 6;  // wave 0..7
  const int L = tid & 63;
  const int quad = L >> 4;
  const int l15 = L & 15;
  const int rl = l15 >> 1;  // cell row-local 0..7
  const int bl = l15 & 1;   // cell batch-local 0..1
  const int b = bg * 2 + bl;
  const int r = R0 + rl;
  const int uq0 = 16 * wv + quad * 4;     // D-side unit base (+reg)
  const int zoff = (4 * wv + quad) * 16;  // zp contiguous 16-half group

  // double-buffered: slot s holds row R0-1+s (s=0..8), per b-local
  __shared__ _Float16 h_lds[2][9 * 2 * HROW];
  for (int i = tid; i < (2 * 9 * 2 * HROW) / 2; i += 512)
    ((unsigned*)h_lds)[i] = 0u;

  // ---- weights as A-fragments, loaded once ----
  v8h wfrag[4][8];
  {
    const v8h* wp8 = (const v8h*)wp;
#pragma unroll
    for (int g = 0; g < 4; g++)
#pragma unroll
      for (int kt = 0; kt < 8; kt++)
        wfrag[g][kt] = wp8[((size_t)((8 * g + wv) * 8 + kt)) * 64 + L];
  }

  float c[4] = {0.f, 0.f, 0.f, 0.f};
  float4 outb[4];  // shift-window out buffer (w-3..w per cell)
#pragma unroll
  for (int i = 0; i < 4; i++) outb[i] = make_float4(0.f, 0.f, 0.f, 0.f);

  const int ebl = L >> 5;       // boundary consumer: b-local
  const int eu = (L & 31) * 4;  // boundary consumer: unit base
  const int exp_idx = bl * 32 + 4 * wv + quad;  // producer slot (l15>=14)

  const bool is_cons = (wv == 0) && (rgr > 0);

  // ---- incremental pointers ----
  const __half* zpp = zph + ((size_t)b * HH + r) * WW * 512 + zoff;
  const __half* zbias = zph + (size_t)BB * HH * WW * 512 + zoff;
  const unsigned long long* ca =
      hx + (((size_t)(rgr > 0 ? rgr - 1 : 0) * 4 + bg) * 64 + L);  // hx[t]
  unsigned long long* pa = hx + (((size_t)rgr * 4 + bg) * 64 + exp_idx);
  float* op0 = out + (((size_t)b * HID + uq0 + 0) * HH + r) * WW;
  float* op1 = out + (((size_t)b * HID + uq0 + 1) * HH + r) * WW;
  float* op2 = out + (((size_t)b * HID + uq0 + 2) * HH + r) * WW;
  float* op3 = out + (((size_t)b * HID + uq0 + 3) * HH + r) * WW;

  // ---- zp for t=0 (w0 = -r: in-band only for r==0) ----
  union ZU {
    uint4 q[2];
    __half h[16];  // h[g*4 + rg2]
  } zu;
  {
    const uint4* p0 = (const uint4*)((r == 0) ? zpp : zbias);
    zu.q[0] = p0[0];
    zu.q[1] = p0[1];
  }
  int wn = 1 - r;  // next-step w
  const __half* zcur = zpp + (ptrdiff_t)wn * 512;

  // ---- boundary pipeline: pend = load of hx[t=0] ----
  unsigned long long pend = 0ull;
  if (is_cons) {
    pend = __hip_atomic_load(ca, __ATOMIC_RELAXED, __HIP_MEMORY_SCOPE_AGENT);
  }

  __syncthreads();

  // 126 = 63x2 steps with static read-buffer index, then epilogue t=126.
  for (int t = 0; t < TT - 1; t += 2) {
    STEP_BODY(t, 0);
    STEP_BODY(t + 1, 1);
  }
  STEP_BODY(TT - 1, 0);
}

// ================= round-1 fallback path (proven correct) =================
__global__ __launch_bounds__(256) void transpose_x(const float* __restrict__ x,
                                                   float* __restrict__ xT) {
  int b = blockIdx.x >> 6;
  int r = blockIdx.x & 63;
  __shared__ float tile[32][65];
  for (int cc = 0; cc < 4; cc++) {
    int cl = threadIdx.x >> 6;
    int w = threadIdx.x & 63;
#pragma unroll
    for (int k = 0; k < 8; k++) {
      int c_loc = k * 4 + cl;
      int c = cc * 32 + c_loc;
      tile[c_loc][w] = x[(((size_t)b * 128 + c) * HH + r) * WW + w];
    }
    __syncthreads();
    int cs = threadIdx.x & 31;
    int wp = threadIdx.x >> 5;
#pragma unroll
    for (int k = 0; k < 8; k++) {
      int w2 = wp * 8 + k;
      xT[(((size_t)b * HH + r) * WW + w2) * 128 + cc * 32 + cs] = tile[cs][w2];
    }
    __syncthreads();
  }
}

__global__ __launch_bounds__(256) void step_kernel(
    const float* __restrict__ x, const float* __restrict__ xT, int use_xT,
    const float* __restrict__ w_is, const float* __restrict__ b_is,
    const float* __restrict__ w_ss, const float* __restrict__ b_ss,
    const float* __restrict__ h_prev, float* __restrict__ h_next,
    float* __restrict__ c_state, float* __restrict__ out, int t) {
  const int rg = blockIdx.x;
  const int q = blockIdx.y;
  const int r0 = rg * 2;
  const int tid = threadIdx.x;
  const int o_loc = tid & 63;
  const int k4 = tid >> 6;
  const int g_ = o_loc >> 4;
  const int u_ = o_loc & 15;
  const int O = g_ * 128 + q * 16 + u_;
  const int i0 = k4 * 32;

  __shared__ __align__(16) float h_in[3][BB][HID];
  __shared__ float zred[16][4][65];

  for (int idx = tid; idx < 3 * BB * HID; idx += 256) {
    int row_sel = idx >> 10;
    int rem = idx & 1023;
    int b = rem >> 7;
    int u = rem & 127;
    int rr = r0 - 1 + row_sel;
    h_in[row_sel][b][u] = (rr >= 0) ? h_prev[((size_t)b * HH + rr) * HID + u] : 0.0f;
  }

  float wr0[32], wr1[32], wz[32];
  {
    const float4* wss4 = (const float4*)(w_ss + ((size_t)O * 128 + i0) * 2);
#pragma unroll
    for (int j = 0; j < 16; j++) {
      float4 v = wss4[j];
      wr0[2 * j] = v.x;
      wr1[2 * j] = v.y;
      wr0[2 * j + 1] = v.z;
      wr1[2 * j + 1] = v.w;
    }
    const float4* wis4 = (const float4*)(w_is + (size_t)O * 128 + i0);
#pragma unroll
    for (int j = 0; j < 8; j++) {
      float4 v = wis4[j];
      wz[4 * j] = v.x;
      wz[4 * j + 1] = v.y;
      wz[4 * j + 2] = v.z;
      wz[4 * j + 3] = v.w;
    }
  }

  __syncthreads();

  float acc[2][BB];
#pragma unroll
  for (int rl = 0; rl < 2; rl++)
#pragma unroll
    for (int b = 0; b < BB; b++) acc[rl][b] = 0.0f;

#pragma unroll
  for (int jb = 0; jb < 8; jb++) {
    int ib = i0 + jb * 4;
#pragma unroll
    for (int b = 0; b < BB; b++) {
      const float4 hm4 = *(const float4*)&h_in[0][b][ib];
      const float4 hc4 = *(const float4*)&h_in[1][b][ib];
      const float4 hp4 = *(const float4*)&h_in[2][b][ib];
      const float* hm = (const float*)&hm4;
      const float* hc = (const float*)&hc4;
      const float* hq = (const float*)&hp4;
#pragma unroll
      for (int jj = 0; jj < 4; jj++) {
        float w0v = wr0[jb * 4 + jj];
        float w1v = wr1[jb * 4 + jj];
        acc[0][b] += w0v * hm[jj] + w1v * hc[jj];
        acc[1][b] += w0v * hc[jj] + w1v * hq[jj];
      }
    }
  }

#pragma unroll
  for (int rl = 0; rl < 2; rl++) {
    int rr = r0 + rl;
    int wcol = t - rr;
    if (wcol >= 0 && wcol < WW) {
      if (use_xT) {
        for (int b = 0; b < BB; b++) {
          const float4* xp =
              (const float4*)(xT + (((size_t)b * HH + rr) * WW + wcol) * 128 + i0);
#pragma unroll
          for (int j = 0; j < 8; j++) {
            float4 v = xp[j];
            acc[rl][b] += wz[4 * j] * v.x + wz[4 * j + 1] * v.y +
                          wz[4 * j + 2] * v.z + wz[4 * j + 3] * v.w;
          }
        }
      } else {
        for (int b = 0; b < BB; b++) {
          const float* xb = x + (((size_t)b * 128 + i0) * HH + rr) * WW + wcol;
#pragma unroll
          for (int j = 0; j < 32; j++) {
            acc[rl][b] += wz[j] * xb[(size_t)j * HH * WW];
          }
        }
      }
    }
  }

#pragma unroll
  for (int rl = 0; rl < 2; rl++)
#pragma unroll
    for (int b = 0; b < BB; b++) zred[rl * 8 + b][k4][o_loc] = acc[rl][b];
  __syncthreads();

  {
    int u = tid >> 4;
    int cell = tid & 15;
    int rl = cell >> 3;
    int b = cell & 7;
    int rr = r0 + rl;
    float z[4];
#pragma unroll
    for (int gg = 0; gg < 4; gg++) {
      int ol = gg * 16 + u;
      float s = zred[cell][0][ol] + zred[cell][1][ol] + zred[cell][2][ol] +
                zred[cell][3][ol];
      int Og = gg * 128 + q * 16 + u;
      z[gg] = s + b_is[Og] + b_ss[Og];
    }
    float iv = 1.0f / (1.0f + expf(-z[0]));
    float fv = 1.0f / (1.0f + expf(-z[1]));
    float ov = 1.0f / (1.0f + expf(-z[2]));
    float gv = tanhf(z[3]);
    int U = q * 16 + u;
    size_t sidx = ((size_t)b * HH + rr) * HID + U;
    float cv = c_state[sidx];
    float cn = fv * cv + iv * gv;
    c_state[sidx] = cn;
    float hn = ov * tanhf(cn);
    h_next[sidx] = hn;
    int wcol = t - rr;
    if (wcol >= 0 && wcol < WW) {
      out[(((size_t)b * HID + U) * HH + rr) * WW + wcol] = hn;
    }
  }
}

extern "C" void kernel_launch(void* const* d_in, const int* in_sizes, int n_in,
                              void* d_out, int out_size, void* d_ws,
                              size_t ws_size, hipStream_t stream) {
  const float* x = (const float*)d_in[0];
  const float* w_is = (const float*)d_in[1];
  const float* b_is = (const float*)d_in[2];
  const float* w_ss = (const float*)d_in[3];
  const float* b_ss = (const float*)d_in[4];
  float* outp = (float*)d_out;

  // zph has one extra 512-half bias slot at pos = B*H*W
  const size_t zph_bytes = ((size_t)BB * HH * WW * 512 + 512) * 2;
  const size_t wp_bytes = (size_t)512 * 256 * 2;  // 256 KiB
  const size_t hx_bytes = (size_t)TT * 8 * 4 * 64 * 8;
  const size_t need = zph_bytes + wp_bytes + hx_bytes;

  char* ws = (char*)d_ws;
  if (ws_size >= need) {
    __half* zph = (__half*)ws;
    _Float16* wpp = (_Float16*)(ws + zph_bytes);
    unsigned long long* hx =
        (unsigned long long*)(ws + zph_bytes + wp_bytes);

    // merged prep + zpre: NPREP prep blocks + 512 zpre blocks
    prep_zpre<<<dim3(NPREP + 512), 256, 0, stream>>>(x, w_is, b_is, b_ss,
                                                     w_ss, wpp, zph, hx);
    lstm_mfma<<<dim3(32), 512, 0, stream>>>(zph, wpp, hx, outp);
  } else {
    // -------- round-1 fallback --------
    const size_t xT_elems = (size_t)BB * HH * WW * 128;
    const size_t st_elems = (size_t)BB * HH * HID;
    const size_t need_xT = (xT_elems + 3 * st_elems) * sizeof(float);
    float* wsf = (float*)d_ws;
    float* xT = nullptr;
    float* st;
    int use_xT = 0;
    if (ws_size >= need_xT) {
      use_xT = 1;
      xT = wsf;
      st = wsf + xT_elems;
    } else {
      st = wsf;
    }
    float* h0 = st;
    float* h1 = st + st_elems;
    float* cb = st + 2 * st_elems;
    hipMemsetAsync(st, 0, 3 * st_elems * sizeof(float), stream);
    if (use_xT) transpose_x<<<dim3(BB * HH), 256, 0, stream>>>(x, xT);
    for (int t = 0; t < TT; t++) {
      float* hp = (t & 1) ? h1 : h0;
      float* hn = (t & 1) ? h0 : h1;
      step_kernel<<<dim3(32, 8), 256, 0, stream>>>(x, xT, use_xT, w_is, b_is,
                                                   w_ss, b_ss, hp, hn, cb, outp,
                                                   t);
    }
  }
}

// Round 5
// 290.868 us; speedup vs baseline: 1.1604x; 1.0791x over previous
//
#include <hip/hip_runtime.h>
#include <hip/hip_fp16.h>
#include <math.h>

// DiagonalLSTM: B=8, Cin=HID=128, H=64, W=64, K=2, T = 2W-1 = 127 steps.
//
// Round 19 design (round 18 + lazy boundary load):
//   - hx boundary load moved from deep prefetch (issued 1.9 steps early,
//     guaranteed to snapshot the sentinel -> spin + L2 round-trip EVERY
//     step, right before the barrier) to a mid-step issue (after the MFMA
//     loop, before gates). Inter-block skew now self-adjusts to a stable
//     lag where the snapshot sees real data: per-step spin cost (~600cy x
//     127 steps) becomes a one-time pipeline-fill skew (7 x ~1400cy).
//     Sentinel spin kept as correctness fallback; newp bookkeeping gone.
//   - otherwise the proven R17/R18 structure: merged prep+zpre kernel
//     (2 launches), z via MFMA C-operand, two independent 4-link MFMA
//     chains, chain-0 ds_reads right after the barrier, LDS-only step
//     barrier (no vmcnt drain), 2x-unrolled t-loop with static buffer
//     indices, bias folded into zph, incremental pointers, reg-buffered
//     out stores, clamp-free fsig/ftanh.

#define HID 128
#define BB 8
#define HH 64
#define WW 64
#define TT 127

// prep item counts: 131072 (wp frags) + 512 (zph bias) + 130048 (hx fill)
//                 = 261632 = 1022 * 256 exactly
#define NPREP 1022

typedef _Float16 v8h __attribute__((ext_vector_type(8)));
typedef float v4f __attribute__((ext_vector_type(4)));

#define SENT64 0xFFFFFFFFFFFFFFFFULL  // 4x f16 -NaN (0xFF fill pattern)

__device__ __forceinline__ float fsig(float x) {
  // saturates correctly at +/-inf without clamping; never NaN
  float e = __builtin_amdgcn_exp2f(x * -1.44269504f);
  return __builtin_amdgcn_rcpf(1.f + e);
}
__device__ __forceinline__ float ftanh_(float x) {
  // 1 - 2/(1+exp2(2x*log2e)): NaN-free at +/-inf (unlike (e-1)/(e+1))
  float e = __builtin_amdgcn_exp2f(x * 2.88539009f);
  return __builtin_fmaf(-2.f, __builtin_amdgcn_rcpf(1.f + e), 1.f);
}

// ---- merged prep + zpre kernel ----
// blocks [0, NPREP): prep items (wp frags, zph bias slot, hx sentinel fill)
// blocks [NPREP, NPREP+512): zpre for (b,r) = bid-NPREP
//   zpre is self-sufficient: converts w_is fragments into registers and
//   computes b_is+b_ss inline -> no dependency on the prep blocks.
__global__ __launch_bounds__(256) void prep_zpre(
    const float* __restrict__ x, const float* __restrict__ w_is,
    const float* __restrict__ b_is, const float* __restrict__ b_ss,
    const float* __restrict__ w_ss, _Float16* __restrict__ wp,
    __half* __restrict__ zph, unsigned long long* __restrict__ hx) {
  const int bid = blockIdx.x;
  const int tid = threadIdx.x;

  __shared__ _Float16 xt[64][136];  // [w][c] f16, padded (zpre half only)

  if (bid < NPREP) {
    int idx = bid * 256 + tid;
    if (idx < 131072) {
      // w_ss -> Wcat(512x256) A-frags: wp[(((mt*8+kt)*64+L)*8+j)]
      int j = idx & 7;
      int L = (idx >> 3) & 63;
      int kt = (idx >> 9) & 7;
      int mt = idx >> 12;  // 0..31
      int O = mt * 16 + (L & 15);
      int k = kt * 32 + ((L >> 4) & 3) * 8 + j;
      float v = (k < 128) ? w_ss[(size_t)O * 256 + k * 2]
                          : w_ss[(size_t)O * 256 + (k - 128) * 2 + 1];
      wp[idx] = (_Float16)v;
    } else if (idx < 131584) {
      // zph bias slot: layout idx2 = (u>>2)*16 + g*4 + (u&3)
      int idx2 = idx - 131072;  // 0..511
      int g = (idx2 >> 2) & 3;
      int u = (idx2 >> 4) * 4 + (idx2 & 3);
      int O = g * 128 + u;
      zph[(size_t)BB * HH * WW * 512 + idx2] = __float2half(b_is[O] + b_ss[O]);
    } else {
      // hx sentinel fill: 260096 u64 as 130048 x 16B
      int j = idx - 131584;
      uint4 s;
      s.x = 0xFFFFFFFFu;
      s.y = 0xFFFFFFFFu;
      s.z = 0xFFFFFFFFu;
      s.w = 0xFFFFFFFFu;
      ((uint4*)hx)[j] = s;
    }
    return;
  }

  // ---------------- zpre half ----------------
  const int zb = bid - NPREP;  // 0..511
  const int b = zb >> 6;
  const int r = zb & 63;
  const int wv = tid >> 6;  // 0..3 -> owns gate wv (mt = 8*wv + m)
  const int L = tid & 63;
  const int quad = L >> 4;
  const int l15 = L & 15;

  // stage x(b,:,r,:) -> xt transposed; coalesced 16-lane c-row reads
  {
    const int cw = tid >> 4;        // c within pass
    const int w4 = (tid & 15) * 4;  // w base
#pragma unroll
    for (int p = 0; p < 8; p++) {
      int c = p * 16 + cw;
      float4 v = *(const float4*)&x[(((size_t)b * 128 + c) * HH + r) * WW + w4];
      xt[w4 + 0][c] = (_Float16)v.x;
      xt[w4 + 1][c] = (_Float16)v.y;
      xt[w4 + 2][c] = (_Float16)v.z;
      xt[w4 + 3][c] = (_Float16)v.w;
    }
  }

  // wave-owned A-frags: convert w_is f32 -> v8h once (overlaps staging)
  // frag lane L, tile (mt,kt) holds w_is[O*128 + kt*32 + quad*8 + (0..7)],
  // O = mt*16 + l15  (identical mapping to the old wisa array)
  v8h wfr[8][4];
  float4 bv[8];
#pragma unroll
  for (int m = 0; m < 8; m++) {
    const int mt = 8 * wv + m;
    const int O = mt * 16 + l15;
#pragma unroll
    for (int kt = 0; kt < 4; kt++) {
      const float* p = w_is + (size_t)O * 128 + kt * 32 + quad * 8;
      float4 a = *(const float4*)p;
      float4 b2 = *(const float4*)(p + 4);
      v8h f;
      f[0] = (_Float16)a.x;
      f[1] = (_Float16)a.y;
      f[2] = (_Float16)a.z;
      f[3] = (_Float16)a.w;
      f[4] = (_Float16)b2.x;
      f[5] = (_Float16)b2.y;
      f[6] = (_Float16)b2.z;
      f[7] = (_Float16)b2.w;
      wfr[m][kt] = f;
    }
    const int O4 = mt * 16 + quad * 4;
    float4 bi = *(const float4*)&b_is[O4];
    float4 bs4 = *(const float4*)&b_ss[O4];
    bv[m] = make_float4(bi.x + bs4.x, bi.y + bs4.y, bi.z + bs4.z, bi.w + bs4.w);
  }

  __syncthreads();

  // 4 n-tiles (w groups of 16); A in regs, B from LDS
#pragma unroll
  for (int nt = 0; nt < 4; nt++) {
    v8h bf[4];
#pragma unroll
    for (int kt = 0; kt < 4; kt++)
      bf[kt] = *(const v8h*)&xt[nt * 16 + l15][kt * 32 + quad * 8];
    const size_t pos = ((size_t)b * HH + r) * WW + nt * 16 + l15;
#pragma unroll
    for (int m = 0; m < 8; m++) {
      v4f acc = (v4f){0.f, 0.f, 0.f, 0.f};
#pragma unroll
      for (int kt = 0; kt < 4; kt++)
        acc = __builtin_amdgcn_mfma_f32_16x16x32_f16(wfr[m][kt], bf[kt], acc,
                                                     0, 0, 0);
      const int mt = 8 * wv + m;  // mt&7 == m, mt>>3 == wv (gate index)
      __half2 lo = __floats2half2_rn(acc[0] + bv[m].x, acc[1] + bv[m].y);
      __half2 hi = __floats2half2_rn(acc[2] + bv[m].z, acc[3] + bv[m].w);
      uint2 pk;
      pk.x = *(unsigned*)&lo;
      pk.y = *(unsigned*)&hi;
      *(uint2*)&zph[pos * 512 + (m * 4 + quad) * 16 + wv * 4] = pk;
    }
  }
}

// ---------------- persistent MFMA recurrent kernel -------------
#define HROW 136  // padded row stride in halfs

// Step barrier: LDS-visibility only (no vmcnt drain; see R15 notes).
#define STEP_BARRIER()                                   \
  do {                                                   \
    asm volatile("s_waitcnt lgkmcnt(0)" ::: "memory");   \
    __builtin_amdgcn_s_barrier();                        \
    asm volatile("" ::: "memory");                       \
  } while (0)

// One recurrence step with compile-time read-buffer index RB (write = RB^1).
// Phase order: chain-0 LDS reads first, z conversion (feeds chain-1's
// C-operand init), zp prefetch, two independent 4-link MFMA chains
// (chain-1 carries z in its accumulator), MID-STEP boundary load (covered
// by gates/pack/stores; steady-state skew makes the snapshot valid),
// gates, exchange / export / out / validate.
#define STEP_BODY(T, RB)                                                       \
  do {                                                                         \
    /* phase 0: chain-0 LDS reads (slot rl) issued ASAP after barrier */       \
    v8h bfr[4];                                                                \
    _Pragma("unroll") for (int kt = 0; kt < 4; kt++)                           \
        bfr[kt] = *(const v8h*)&h_lds[RB][(rl * 2 + bl) * HROW + kt * 32 +     \
                                          quad * 8];                           \
    /* convert zu -> v4f (chain-1 C-operand init; single use per value) */     \
    v4f zi[4];                                                                 \
    _Pragma("unroll") for (int g = 0; g < 4; g++)                              \
        _Pragma("unroll") for (int i = 0; i < 4; i++)                          \
        zi[g][i] = __half2float(zu.h[g * 4 + i]);                              \
    /* zp prefetch for T+1 (contiguous 32B; bias slot when out-of-band) */     \
    {                                                                          \
      const uint4* p = (const uint4*)(((unsigned)wn < WW) ? zcur : zbias);     \
      zu.q[0] = p[0];                                                          \
      zu.q[1] = p[1];                                                          \
      wn++;                                                                    \
      zcur += 512;                                                             \
    }                                                                          \
    /* MFMA: two independent 4-link chains; chain-1 accumulates onto z */      \
    v4f acc0[4], acc1[4];                                                      \
    _Pragma("unroll") for (int g = 0; g < 4; g++) {                            \
      acc0[g] = (v4f){0.f, 0.f, 0.f, 0.f};                                     \
      acc1[g] = zi[g];                                                         \
    }                                                                          \
    _Pragma("unroll") for (int kt = 0; kt < 4; kt++) {                         \
      _Pragma("unroll") for (int g = 0; g < 4; g++)                            \
          acc0[g] = __builtin_amdgcn_mfma_f32_16x16x32_f16(                    \
              wfrag[g][kt], bfr[kt], acc0[g], 0, 0, 0);                        \
    }                                                                          \
    _Pragma("unroll") for (int kt = 0; kt < 4; kt++) {                         \
      v8h bf1 = *(const v8h*)&h_lds[RB][((rl + 1) * 2 + bl) * HROW + kt * 32 + \
                                        quad * 8];                             \
      _Pragma("unroll") for (int g = 0; g < 4; g++)                            \
          acc1[g] = __builtin_amdgcn_mfma_f32_16x16x32_f16(                    \
              wfrag[g][4 + kt], bf1, acc1[g], 0, 0, 0);                        \
    }                                                                          \
    /* mid-step boundary load: hx[T] (validated before the barrier below).    \
       Issued here so gate/pack/store work (~1000cy) covers the L2 round      \
       trip; block skew self-adjusts so this snapshot sees real data. */      \
    unsigned long long pend = 0ull;                                            \
    if (is_cons)                                                               \
      pend = __hip_atomic_load(ca, __ATOMIC_RELAXED,                           \
                               __HIP_MEMORY_SCOPE_AGENT);                      \
    /* gates (bias pre-folded into zph -> rides in acc1) */                    \
    const int w = (T)-r;                                                       \
    const bool inband = ((unsigned)w < WW);                                    \
    float hv[4];                                                               \
    _Pragma("unroll") for (int rg2 = 0; rg2 < 4; rg2++) {                      \
      float z0 = acc0[0][rg2] + acc1[0][rg2];                                  \
      float z1 = acc0[1][rg2] + acc1[1][rg2];                                  \
      float z2 = acc0[2][rg2] + acc1[2][rg2];                                  \
      float z3 = acc0[3][rg2] + acc1[3][rg2];                                  \
      float iv = fsig(z0);                                                     \
      float fv = fsig(z1);                                                     \
      float ov = fsig(z2);                                                     \
      float gv = ftanh_(z3);                                                   \
      c[rg2] = fv * c[rg2] + iv * gv;                                          \
      hv[rg2] = ov * ftanh_(c[rg2]);                                           \
    }                                                                          \
    /* h(T) -> write-buffer slots 1..8 (LDS, 8B per lane) */                   \
    __half2 plo = __floats2half2_rn(hv[0], hv[1]);                             \
    __half2 phi = __floats2half2_rn(hv[2], hv[3]);                             \
    {                                                                          \
      uint2 pk;                                                                \
      pk.x = *(unsigned*)&plo;                                                 \
      pk.y = *(unsigned*)&phi;                                                 \
      *(uint2*)&h_lds[(RB) ^ 1][((rl + 1) * 2 + bl) * HROW + uq0] = pk;        \
    }                                                                          \
    /* export h(T)[R0+7]: fire-and-forget (data == flag, no drain) */          \
    if (rgr < 7 && l15 >= 14) {                                                \
      unsigned long long pk =                                                  \
          ((unsigned long long)*(unsigned*)&phi << 32) | *(unsigned*)&plo;     \
      __hip_atomic_store(pa, pk, __ATOMIC_RELAXED, __HIP_MEMORY_SCOPE_AGENT);  \
    }                                                                          \
    pa += 2048;                                                                \
    /* out shift-window; coalesced 16B flush every 4 steps per cell */         \
    _Pragma("unroll") for (int rg2 = 0; rg2 < 4; rg2++) {                      \
      outb[rg2].x = outb[rg2].y;                                               \
      outb[rg2].y = outb[rg2].z;                                               \
      outb[rg2].z = outb[rg2].w;                                               \
      outb[rg2].w = hv[rg2];                                                   \
    }                                                                          \
    if (inband && (w & 3) == 3) {                                              \
      *(float4*)op0 = outb[0];                                                 \
      *(float4*)op1 = outb[1];                                                 \
      *(float4*)op2 = outb[2];                                                 \
      *(float4*)op3 = outb[3];                                                 \
      op0 += 4;                                                                \
      op1 += 4;                                                                \
      op2 += 4;                                                                \
      op3 += 4;                                                                \
    }                                                                          \
    /* validate pend (hx[T] = h(T)[R0-1]), write to wb slot 0 */               \
    if (is_cons) {                                                             \
      while (__ballot(pend == SENT64) != 0ull) {                               \
        __builtin_amdgcn_s_sleep(1);                                           \
        pend = __hip_atomic_load(ca, __ATOMIC_RELAXED,                         \
                                 __HIP_MEMORY_SCOPE_AGENT);                    \
      }                                                                        \
      *(unsigned long long*)&h_lds[(RB) ^ 1][(0 * 2 + ebl) * HROW + eu] =      \
          pend;                                                                \
    }                                                                          \
    ca += 2048;                                                                \
    STEP_BARRIER();                                                            \
  } while (0)

__global__ __launch_bounds__(512, 1) void lstm_mfma(
    const __half* __restrict__ zph, const _Float16* __restrict__ wp,
    unsigned long long* __restrict__ hx,  // [TT][8][4][64], sentinel-filled
    float* __restrict__ out) {
  const int blk = blockIdx.x;  // 0..31
  const int rgr = blk >> 2;    // row group 0..7 (rows 8*rgr .. +7)
  const int bg = blk & 3;      // batch group 0..3 (b = 2*bg, 2*bg+1)
  const int R0 = rgr * 8;
  const int tid = threadIdx.x;
  const int wv = tid >> 6;  // wave 0..7
  const int L = tid & 63;
  const int quad = L >> 4;
  const int l15 = L & 15;
  const int rl = l15 >> 1;  // cell row-local 0..7
  const int bl = l15 & 1;   // cell batch-local 0..1
  const int b = bg * 2 + bl;
  const int r = R0 + rl;
  const int uq0 = 16 * wv + quad * 4;     // D-side unit base (+reg)
  const int zoff = (4 * wv + quad) * 16;  // zp contiguous 16-half group

  // double-buffered: slot s holds row R0-1+s (s=0..8), per b-local
  __shared__ _Float16 h_lds[2][9 * 2 * HROW];
  for (int i = tid; i < (2 * 9 * 2 * HROW) / 2; i += 512)
    ((unsigned*)h_lds)[i] = 0u;

  // ---- weights as A-fragments, loaded once ----
  v8h wfrag[4][8];
  {
    const v8h* wp8 = (const v8h*)wp;
#pragma unroll
    for (int g = 0; g < 4; g++)
#pragma unroll
      for (int kt = 0; kt < 8; kt++)
        wfrag[g][kt] = wp8[((size_t)((8 * g + wv) * 8 + kt)) * 64 + L];
  }

  float c[4] = {0.f, 0.f, 0.f, 0.f};
  float4 outb[4];  // shift-window out buffer (w-3..w per cell)
#pragma unroll
  for (int i = 0; i < 4; i++) outb[i] = make_float4(0.f, 0.f, 0.f, 0.f);

  const int ebl = L >> 5;       // boundary consumer: b-local
  const int eu = (L & 31) * 4;  // boundary consumer: unit base
  const int exp_idx = bl * 32 + 4 * wv + quad;  // producer slot (l15>=14)

  const bool is_cons = (wv == 0) && (rgr > 0);

  // ---- incremental pointers ----
  const __half* zpp = zph + ((size_t)b * HH + r) * WW * 512 + zoff;
  const __half* zbias = zph + (size_t)BB * HH * WW * 512 + zoff;
  const unsigned long long* ca =
      hx + (((size_t)(rgr > 0 ? rgr - 1 : 0) * 4 + bg) * 64 + L);  // hx[t]
  unsigned long long* pa = hx + (((size_t)rgr * 4 + bg) * 64 + exp_idx);
  float* op0 = out + (((size_t)b * HID + uq0 + 0) * HH + r) * WW;
  float* op1 = out + (((size_t)b * HID + uq0 + 1) * HH + r) * WW;
  float* op2 = out + (((size_t)b * HID + uq0 + 2) * HH + r) * WW;
  float* op3 = out + (((size_t)b * HID + uq0 + 3) * HH + r) * WW;

  // ---- zp for t=0 (w0 = -r: in-band only for r==0) ----
  union ZU {
    uint4 q[2];
    __half h[16];  // h[g*4 + rg2]
  } zu;
  {
    const uint4* p0 = (const uint4*)((r == 0) ? zpp : zbias);
    zu.q[0] = p0[0];
    zu.q[1] = p0[1];
  }
  int wn = 1 - r;  // next-step w
  const __half* zcur = zpp + (ptrdiff_t)wn * 512;

  __syncthreads();

  // 126 = 63x2 steps with static read-buffer index, then epilogue t=126.
  for (int t = 0; t < TT - 1; t += 2) {
    STEP_BODY(t, 0);
    STEP_BODY(t + 1, 1);
  }
  STEP_BODY(TT - 1, 0);
}

// ================= round-1 fallback path (proven correct) =================
__global__ __launch_bounds__(256) void transpose_x(const float* __restrict__ x,
                                                   float* __restrict__ xT) {
  int b = blockIdx.x >> 6;
  int r = blockIdx.x & 63;
  __shared__ float tile[32][65];
  for (int cc = 0; cc < 4; cc++) {
    int cl = threadIdx.x >> 6;
    int w = threadIdx.x & 63;
#pragma unroll
    for (int k = 0; k < 8; k++) {
      int c_loc = k * 4 + cl;
      int c = cc * 32 + c_loc;
      tile[c_loc][w] = x[(((size_t)b * 128 + c) * HH + r) * WW + w];
    }
    __syncthreads();
    int cs = threadIdx.x & 31;
    int wp = threadIdx.x >> 5;
#pragma unroll
    for (int k = 0; k < 8; k++) {
      int w2 = wp * 8 + k;
      xT[(((size_t)b * HH + r) * WW + w2) * 128 + cc * 32 + cs] = tile[cs][w2];
    }
    __syncthreads();
  }
}

__global__ __launch_bounds__(256) void step_kernel(
    const float* __restrict__ x, const float* __restrict__ xT, int use_xT,
    const float* __restrict__ w_is, const float* __restrict__ b_is,
    const float* __restrict__ w_ss, const float* __restrict__ b_ss,
    const float* __restrict__ h_prev, float* __restrict__ h_next,
    float* __restrict__ c_state, float* __restrict__ out, int t) {
  const int rg = blockIdx.x;
  const int q = blockIdx.y;
  const int r0 = rg * 2;
  const int tid = threadIdx.x;
  const int o_loc = tid & 63;
  const int k4 = tid >> 6;
  const int g_ = o_loc >> 4;
  const int u_ = o_loc & 15;
  const int O = g_ * 128 + q * 16 + u_;
  const int i0 = k4 * 32;

  __shared__ __align__(16) float h_in[3][BB][HID];
  __shared__ float zred[16][4][65];

  for (int idx = tid; idx < 3 * BB * HID; idx += 256) {
    int row_sel = idx >> 10;
    int rem = idx & 1023;
    int b = rem >> 7;
    int u = rem & 127;
    int rr = r0 - 1 + row_sel;
    h_in[row_sel][b][u] = (rr >= 0) ? h_prev[((size_t)b * HH + rr) * HID + u] : 0.0f;
  }

  float wr0[32], wr1[32], wz[32];
  {
    const float4* wss4 = (const float4*)(w_ss + ((size_t)O * 128 + i0) * 2);
#pragma unroll
    for (int j = 0; j < 16; j++) {
      float4 v = wss4[j];
      wr0[2 * j] = v.x;
      wr1[2 * j] = v.y;
      wr0[2 * j + 1] = v.z;
      wr1[2 * j + 1] = v.w;
    }
    const float4* wis4 = (const float4*)(w_is + (size_t)O * 128 + i0);
#pragma unroll
    for (int j = 0; j < 8; j++) {
      float4 v = wis4[j];
      wz[4 * j] = v.x;
      wz[4 * j + 1] = v.y;
      wz[4 * j + 2] = v.z;
      wz[4 * j + 3] = v.w;
    }
  }

  __syncthreads();

  float acc[2][BB];
#pragma unroll
  for (int rl = 0; rl < 2; rl++)
#pragma unroll
    for (int b = 0; b < BB; b++) acc[rl][b] = 0.0f;

#pragma unroll
  for (int jb = 0; jb < 8; jb++) {
    int ib = i0 + jb * 4;
#pragma unroll
    for (int b = 0; b < BB; b++) {
      const float4 hm4 = *(const float4*)&h_in[0][b][ib];
      const float4 hc4 = *(const float4*)&h_in[1][b][ib];
      const float4 hp4 = *(const float4*)&h_in[2][b][ib];
      const float* hm = (const float*)&hm4;
      const float* hc = (const float*)&hc4;
      const float* hq = (const float*)&hp4;
#pragma unroll
      for (int jj = 0; jj < 4; jj++) {
        float w0v = wr0[jb * 4 + jj];
        float w1v = wr1[jb * 4 + jj];
        acc[0][b] += w0v * hm[jj] + w1v * hc[jj];
        acc[1][b] += w0v * hc[jj] + w1v * hq[jj];
      }
    }
  }

#pragma unroll
  for (int rl = 0; rl < 2; rl++) {
    int rr = r0 + rl;
    int wcol = t - rr;
    if (wcol >= 0 && wcol < WW) {
      if (use_xT) {
        for (int b = 0; b < BB; b++) {
          const float4* xp =
              (const float4*)(xT + (((size_t)b * HH + rr) * WW + wcol) * 128 + i0);
#pragma unroll
          for (int j = 0; j < 8; j++) {
            float4 v = xp[j];
            acc[rl][b] += wz[4 * j] * v.x + wz[4 * j + 1] * v.y +
                          wz[4 * j + 2] * v.z + wz[4 * j + 3] * v.w;
          }
        }
      } else {
        for (int b = 0; b < BB; b++) {
          const float* xb = x + (((size_t)b * 128 + i0) * HH + rr) * WW + wcol;
#pragma unroll
          for (int j = 0; j < 32; j++) {
            acc[rl][b] += wz[j] * xb[(size_t)j * HH * WW];
          }
        }
      }
    }
  }

#pragma unroll
  for (int rl = 0; rl < 2; rl++)
#pragma unroll
    for (int b = 0; b < BB; b++) zred[rl * 8 + b][k4][o_loc] = acc[rl][b];
  __syncthreads();

  {
    int u = tid >> 4;
    int cell = tid & 15;
    int rl = cell >> 3;
    int b = cell & 7;
    int rr = r0 + rl;
    float z[4];
#pragma unroll
    for (int gg = 0; gg < 4; gg++) {
      int ol = gg * 16 + u;
      float s = zred[cell][0][ol] + zred[cell][1][ol] + zred[cell][2][ol] +
                zred[cell][3][ol];
      int Og = gg * 128 + q * 16 + u;
      z[gg] = s + b_is[Og] + b_ss[Og];
    }
    float iv = 1.0f / (1.0f + expf(-z[0]));
    float fv = 1.0f / (1.0f + expf(-z[1]));
    float ov = 1.0f / (1.0f + expf(-z[2]));
    float gv = tanhf(z[3]);
    int U = q * 16 + u;
    size_t sidx = ((size_t)b * HH + rr) * HID + U;
    float cv = c_state[sidx];
    float cn = fv * cv + iv * gv;
    c_state[sidx] = cn;
    float hn = ov * tanhf(cn);
    h_next[sidx] = hn;
    int wcol = t - rr;
    if (wcol >= 0 && wcol < WW) {
      out[(((size_t)b * HID + U) * HH + rr) * WW + wcol] = hn;
    }
  }
}

extern "C" void kernel_launch(void* const* d_in, const int* in_sizes, int n_in,
                              void* d_out, int out_size, void* d_ws,
                              size_t ws_size, hipStream_t stream) {
  const float* x = (const float*)d_in[0];
  const float* w_is = (const float*)d_in[1];
  const float* b_is = (const float*)d_in[2];
  const float* w_ss = (const float*)d_in[3];
  const float* b_ss = (const float*)d_in[4];
  float* outp = (float*)d_out;

  // zph has one extra 512-half bias slot at pos = B*H*W
  const size_t zph_bytes = ((size_t)BB * HH * WW * 512 + 512) * 2;
  const size_t wp_bytes = (size_t)512 * 256 * 2;  // 256 KiB
  const size_t hx_bytes = (size_t)TT * 8 * 4 * 64 * 8;
  const size_t need = zph_bytes + wp_bytes + hx_bytes;

  char* ws = (char*)d_ws;
  if (ws_size >= need) {
    __half* zph = (__half*)ws;
    _Float16* wpp = (_Float16*)(ws + zph_bytes);
    unsigned long long* hx =
        (unsigned long long*)(ws + zph_bytes + wp_bytes);

    // merged prep + zpre: NPREP prep blocks + 512 zpre blocks
    prep_zpre<<<dim3(NPREP + 512), 256, 0, stream>>>(x, w_is, b_is, b_ss,
                                                     w_ss, wpp, zph, hx);
    lstm_mfma<<<dim3(32), 512, 0, stream>>>(zph, wpp, hx, outp);
  } else {
    // -------- round-1 fallback --------
    const size_t xT_elems = (size_t)BB * HH * WW * 128;
    const size_t st_elems = (size_t)BB * HH * HID;
    const size_t need_xT = (xT_elems + 3 * st_elems) * sizeof(float);
    float* wsf = (float*)d_ws;
    float* xT = nullptr;
    float* st;
    int use_xT = 0;
    if (ws_size >= need_xT) {
      use_xT = 1;
      xT = wsf;
      st = wsf + xT_elems;
    } else {
      st = wsf;
    }
    float* h0 = st;
    float* h1 = st + st_elems;
    float* cb = st + 2 * st_elems;
    hipMemsetAsync(st, 0, 3 * st_elems * sizeof(float), stream);
    if (use_xT) transpose_x<<<dim3(BB * HH), 256, 0, stream>>>(x, xT);
    for (int t = 0; t < TT; t++) {
      float* hp = (t & 1) ? h1 : h0;
      float* hn = (t & 1) ? h0 : h1;
      step_kernel<<<dim3(32, 8), 256, 0, stream>>>(x, xT, use_xT, w_is, b_is,
                                                   w_ss, b_ss, hp, hn, cb, outp,
                                                   t);
    }
  }
}